// Round 8
// baseline (181.808 us; speedup 1.0000x reference)
//
#include <hip/hip_runtime.h>
#include <stdint.h>

#define B_ 4
#define L_ 2048
#define D_ 1024
#define H_ 16
#define DK_ 64

typedef __attribute__((ext_vector_type(8))) short bf16x8;
typedef __attribute__((ext_vector_type(4))) float f32x4;
typedef unsigned short bfu;   // raw bf16 storage

#define MFMA(a, b, c) __builtin_amdgcn_mfma_f32_16x16x32_bf16((a), (b), (c), 0, 0, 0)

__device__ __forceinline__ unsigned short f2bf(float f) {
  union { float f; unsigned int u; } v; v.f = f;
  unsigned int u = v.u;
  return (unsigned short)((u + 0x7fffu + ((u >> 16) & 1u)) >> 16);  // RNE
}

__device__ __forceinline__ void gll16(const void* g, void* l) {
  __builtin_amdgcn_global_load_lds(
      (const __attribute__((address_space(1))) void*)g,
      (__attribute__((address_space(3))) void*)l, 16, 0, 0);
}

#define VMCNT(n_) asm volatile("s_waitcnt vmcnt(" #n_ ")" ::: "memory")
#define BARRIER() asm volatile("s_barrier" ::: "memory")

template <int N> __device__ __forceinline__ void vmwait() {
  static_assert(N >= 0 && N <= 8, "vmcnt range");
  if constexpr (N == 0) VMCNT(0);
  else if constexpr (N == 1) VMCNT(1);
  else if constexpr (N == 2) VMCNT(2);
  else if constexpr (N == 3) VMCNT(3);
  else if constexpr (N == 4) VMCNT(4);
  else if constexpr (N == 5) VMCNT(5);
  else if constexpr (N == 6) VMCNT(6);
  else if constexpr (N == 7) VMCNT(7);
  else VMCNT(8);
}

// ---------------- prep kernels ----------------

__global__ __launch_bounds__(256) void cast_x(const float* __restrict__ in,
                                              bfu* __restrict__ out, int n4) {
  int i = blockIdx.x * 256 + threadIdx.x;
  if (i >= n4) return;
  float4 v = ((const float4*)in)[i];
  ushort4 o;
  o.x = f2bf(v.x); o.y = f2bf(v.y); o.z = f2bf(v.z); o.w = f2bf(v.w);
  ((ushort4*)out)[i] = o;
}

// in[R][C] fp32 -> out[C][R] bf16
__global__ void transpose_cast(const float* __restrict__ in, bfu* __restrict__ out,
                               int R, int C) {
  __shared__ float tile[32][33];
  int c0 = blockIdx.x * 32, r0 = blockIdx.y * 32;
  int tx = threadIdx.x, ty = threadIdx.y;  // 32 x 8
#pragma unroll
  for (int i = ty; i < 32; i += 8)
    tile[i][tx] = in[(size_t)(r0 + i) * C + c0 + tx];
  __syncthreads();
#pragma unroll
  for (int i = ty; i < 32; i += 8)
    out[(size_t)(c0 + i) * R + r0 + tx] = f2bf(tile[tx][i]);
}

// ---------------- BMxBN 4-phase BT GEMM, WMxWN waves, 2 blocks/CU ----------
// C[M][N] = A[M][K] * Bt[N][K]^T. 512 threads = 8 waves (WM x WN), per-wave
// output RM x RN. BK=64, double-buffered LDS (BM=BN=128 -> 32KB -> 2 blk/CU).
// Stage units: LO = A-lo+B-lo (p0), B-hi (p1), A-hi (p2); each waited 3
// phases after issue. EPI 0: scatter Q (scaled log2e/8), K, V (via LDS
// sigma^-1-permuted transpose, BN=BM=128 single pass). EPI 1: fp32 += bias.

template <int EPI, int BM, int BN, int WM, int WN>
__global__ __launch_bounds__(512, 4) void gemm8(
    const bfu* __restrict__ A, const bfu* __restrict__ Bt,
    const float* __restrict__ bias, bfu* __restrict__ Qg, bfu* __restrict__ Kg,
    bfu* __restrict__ Vtg, float* __restrict__ Out, int M, int N, int K) {
  __shared__ __align__(16) bfu LDSb[(BM + BN) * 128];  // A[2] then B[2]
  constexpr int RM = BM / WM, RN = BN / WN;
  constexpr int MH = RM / 32, NH = RN / 32;   // frags per half
  constexpr int HA = BM / 128, HB = BN / 128; // loads/thread per half-unit
  constexpr int LO = HA + HB;

  const int tid = threadIdx.x;
  const int lane = tid & 63;
  const int w = tid >> 6;
  const int wm = w / WN, wn = w % WN;
  const int l15 = lane & 15, l4 = lane >> 4;

  // XCD-bijective swizzle; m-fastest so consecutive swz share the B-panel
  const int nwg = gridDim.x;
  const int cpx = nwg >> 3;
  const int bid = (int)blockIdx.x;
  const int swz = (bid & 7) * cpx + (bid >> 3);
  const int MT = M / BM;
  const int m0 = (swz % MT) * BM;
  const int n0 = (swz / MT) * BN;

  auto stageA = [&](int t, int half) {
    bfu* lb = LDSb + (t & 1) * (BM * 64);
#pragma unroll
    for (int j = 0; j < HA; ++j) {
      int idx = j * 512 + tid;
      int u = idx >> 3;  // [0, BM/2)
      int row = half * (RM / 2) + (u & (RM / 2 - 1)) + (u / (RM / 2)) * RM;
      int c16 = (idx & 7) ^ (row & 7);
      gll16(A + (size_t)(m0 + row) * K + t * 64 + c16 * 8,
            (char*)lb + row * 128 + (idx & 7) * 16);
    }
  };
  auto stageB = [&](int t, int half) {
    bfu* lb = LDSb + 2 * BM * 64 + (t & 1) * (BN * 64);
#pragma unroll
    for (int j = 0; j < HB; ++j) {
      int idx = j * 512 + tid;
      int u = idx >> 3;  // [0, BN/2)
      int row = half * (RN / 2) + (u & (RN / 2 - 1)) + (u / (RN / 2)) * RN;
      int c16 = (idx & 7) ^ (row & 7);
      gll16(Bt + (size_t)(n0 + row) * K + t * 64 + c16 * 8,
            (char*)lb + row * 128 + (idx & 7) * 16);
    }
  };

  f32x4 acc[2 * MH][2 * NH] = {};
  bf16x8 af[MH][2], bfLO[NH][2], bfHI[NH][2];

  auto lda = [&](int c, int half) {
    const char* base = (const char*)(LDSb + c * (BM * 64));
#pragma unroll
    for (int mi = 0; mi < MH; ++mi)
#pragma unroll
      for (int kk = 0; kk < 2; ++kk) {
        int row = wm * RM + half * (RM / 2) + mi * 16 + l15;
        int ch = (kk * 4 + l4) ^ (row & 7);
        af[mi][kk] = *(const bf16x8*)(base + row * 128 + ch * 16);
      }
  };
  auto ldb = [&](int c, int half, bf16x8 (&dst)[NH][2]) {
    const char* base = (const char*)(LDSb + 2 * BM * 64 + c * (BN * 64));
#pragma unroll
    for (int ni = 0; ni < NH; ++ni)
#pragma unroll
      for (int kk = 0; kk < 2; ++kk) {
        int row = wn * RN + half * (RN / 2) + ni * 16 + l15;
        int ch = (kk * 4 + l4) ^ (row & 7);
        dst[ni][kk] = *(const bf16x8*)(base + row * 128 + ch * 16);
      }
  };
  auto mm = [&](int mo, int no, bf16x8 (&bx)[NH][2]) {
    __builtin_amdgcn_s_setprio(1);
#pragma unroll
    for (int mi = 0; mi < MH; ++mi)
#pragma unroll
      for (int ni = 0; ni < NH; ++ni)
#pragma unroll
        for (int kk = 0; kk < 2; ++kk)
          acc[mo + mi][no + ni] = MFMA(af[mi][kk], bx[ni][kk], acc[mo + mi][no + ni]);
    __builtin_amdgcn_s_setprio(0);
  };

  // ---- prologue: stage tile 0 units in order LO(A-lo,B-lo), B-hi, A-hi
  stageA(0, 0); stageB(0, 0); stageB(0, 1); stageA(0, 1);
  vmwait<HB + HA>();   // retires LO(0); B-hi(0), A-hi(0) stay in flight
  BARRIER();

  const int NT = K >> 6;
  for (int t = 0; t < NT - 1; ++t) {
    const int c = t & 1, tn = t + 1;
    // p0: quadrant (lo,lo)
    lda(c, 0); ldb(c, 0, bfLO);
    stageA(tn, 0); stageB(tn, 0);      // LO(t+1)
    mm(0, 0, bfLO);
    vmwait<HA + LO>(); BARRIER();      // retires BHI(t)
    // p1: quadrant (lo,hi)
    ldb(c, 1, bfHI);
    stageB(tn, 1);                     // BHI(t+1)
    mm(0, NH, bfHI);
    vmwait<LO + HB>(); BARRIER();      // retires AHI(t)
    // p2: quadrant (hi,hi)
    lda(c, 1);
    stageA(tn, 1);                     // AHI(t+1)
    mm(MH, NH, bfHI);
    BARRIER();                         // no wait
    // p3: quadrant (hi,lo) — no ds_reads (bfLO live)
    mm(MH, 0, bfLO);
    vmwait<HB + HA>(); BARRIER();      // retires LO(t+1)
  }
  {  // peeled last K-tile: outstanding on entry = {BHI(t), AHI(t)}
    const int c = (NT - 1) & 1;
    lda(c, 0); ldb(c, 0, bfLO);
    mm(0, 0, bfLO);
    vmwait<HA>(); BARRIER();           // retires BHI(t)
    ldb(c, 1, bfHI);
    mm(0, NH, bfHI);
    vmwait<0>(); BARRIER();            // retires AHI(t)
    lda(c, 1);
    mm(MH, NH, bfHI);
    mm(MH, 0, bfLO);
  }

  // ---- epilogue: C/D layout col = lane&15, row = (lane>>4)*4 + reg
  if constexpr (EPI == 1) {
#pragma unroll
    for (int ni = 0; ni < 2 * NH; ++ni) {
      int gn = n0 + wn * RN + ni * 16 + l15;
      float bv = bias[gn];
#pragma unroll
      for (int mi = 0; mi < 2 * MH; ++mi)
#pragma unroll
        for (int rg = 0; rg < 4; ++rg) {
          int gm = m0 + wm * RM + mi * 16 + l4 * 4 + rg;
          Out[(size_t)gm * N + gn] = acc[mi][ni][rg] + bv;
        }
    }
  } else {
    const int sec = n0 >> 10;  // 0: Q, 1: K, 2: V sections (1024-wide)
    if (sec < 2) {
      bfu* dst = (sec == 0) ? Qg : Kg;
      const float scale = (sec == 0) ? 0.18033688011112042f : 1.0f;  // log2e/8
#pragma unroll
      for (int ni = 0; ni < 2 * NH; ++ni) {
        int gn = n0 + wn * RN + ni * 16 + l15;
        int rem = gn & 1023;
        int hh = rem >> 6, dk = rem & 63;
        float bv = bias[gn];
#pragma unroll
        for (int mi = 0; mi < 2 * MH; ++mi)
#pragma unroll
          for (int rg = 0; rg < 4; ++rg) {
            int gm = m0 + wm * RM + mi * 16 + l4 * 4 + rg;
            int bb = gm >> 11, ll = gm & 2047;
            dst[(((size_t)(bb * H_ + hh)) * L_ + ll) * DK_ + dk] =
                f2bf((acc[mi][ni][rg] + bv) * scale);
          }
      }
    } else {
      // V: transpose via LDS with sigma^-1 kv-permutation (single pass:
      // BN x BM x 2B = 32KB fits LDSb). Row stride BM*2 = 256B.
      __syncthreads();  // K-loop LDS reads done everywhere
#pragma unroll
      for (int ni = 0; ni < 2 * NH; ++ni) {
        int n_local = wn * RN + ni * 16 + l15;
        int gn = n0 + n_local;
        float bv = bias[gn];
        int swzn = (n_local & 7) << 4;
#pragma unroll
        for (int mi = 0; mi < 2 * MH; ++mi) {
          int m_base = wm * RM + mi * 16 + l4 * 4;
          int k6 = m_base & 63;
          int p0 = (m_base & ~63) |
                   ((k6 & 32) | (((k6 >> 2) & 3) << 3) | (((k6 >> 4) & 1) << 2));
          float v0 = acc[mi][ni][0] + bv, v1 = acc[mi][ni][1] + bv;
          float v2 = acc[mi][ni][2] + bv, v3 = acc[mi][ni][3] + bv;
          uint32_t w01, w23;
          asm("v_cvt_pk_bf16_f32 %0, %1, %2" : "=v"(w01) : "v"(v0), "v"(v1));
          asm("v_cvt_pk_bf16_f32 %0, %1, %2" : "=v"(w23) : "v"(v2), "v"(v3));
          *(uint32_t*)((char*)LDSb + n_local * (BM * 2) + ((2 * p0) ^ swzn)) = w01;
          *(uint32_t*)((char*)LDSb + n_local * (BM * 2) + ((2 * p0 + 4) ^ swzn)) = w23;
        }
      }
      __syncthreads();
      // readers: 512 threads, 4 per n-row (BN=128), 4 x 16B chunks each
      int n = tid >> 2;
      int cb = (tid & 3) * 4;
      int gnn = n0 + n;
      int hh = (gnn >> 6) & 15, dk = gnn & 63;
      size_t rowbase =
          (((size_t)((m0 >> 11) * H_ + hh)) * DK_ + dk) * L_ + (m0 & 2047);
#pragma unroll
      for (int j = 0; j < 4; ++j) {
        int ch = cb + j;
        bf16x8 vv = *(const bf16x8*)((char*)LDSb + n * (BM * 2) +
                                     ((ch * 16) ^ ((n & 7) << 4)));
        *(bf16x8*)(Vtg + rowbase + ch * 8) = vv;
      }
    }
  }
}

// ---------------- flash attention v3 (causal) ----------------
// 512 blocks; xcd = hid&7, 8 bh per XCD (K/V L2 locality). Block handles
// 128-row q-superblocks {p, 15-p} (34 KV tiles, perfect balance). 4 waves;
// wave owns 32 q rows (2 x 16). Q loaded directly to registers (no Q LDS).
// S^T = mfma(K,Q): lane owns softmax stats of one q-row per half. V stored
// sigma-permuted so packed P words ARE the PV A-fragment (no cross-lane).

__global__ __launch_bounds__(256, 3) void attn(const bfu* __restrict__ Qg,
                                               const bfu* __restrict__ Kg,
                                               const bfu* __restrict__ Vtg,
                                               bfu* __restrict__ Ao) {
  __shared__ __align__(16) bfu Ks[2 * 64 * 64];
  __shared__ __align__(16) bfu Vs[2 * 64 * 64];

  const int tid = threadIdx.x;
  const int lane = tid & 63;
  const int w = tid >> 6;
  const int l15 = lane & 15, l4 = lane >> 4;

  const int hid = blockIdx.x;            // 512 blocks
  const int xcd = hid & 7, slot = hid >> 3;
  const int bh = xcd * 8 + (slot >> 3);  // 8 bh per XCD
  const int p = slot & 7;
  const int b = bh >> 4, h = bh & 15;

  for (int seg = 0; seg < 2; ++seg) {
    const int qb = (seg == 0) ? p : 15 - p;   // 128-row superblock
    const int q0 = qb * 128;
    const int nt = 2 * qb + 2;
    const int q0w = q0 + w * 32;              // wave's first q row

    // ---- Q fragments straight from global (Qg pre-scaled by log2e/8)
    bf16x8 qf[2][2];
#pragma unroll
    for (int mi = 0; mi < 2; ++mi)
#pragma unroll
      for (int kk = 0; kk < 2; ++kk)
        qf[mi][kk] = *(const bf16x8*)(
            Qg + ((size_t)bh * L_ + q0w + mi * 16 + l15) * DK_ + kk * 32 + l4 * 8);

    // ---- stage KV tile 0 (buffer 0)
#pragma unroll
    for (int i = 0; i < 2; ++i) {
      int lb = i * 256 + tid;
      int r = lb >> 3, c16 = (lb & 7) ^ (r & 7);
      gll16(Kg + ((size_t)bh * L_ + r) * DK_ + c16 * 8, (char*)Ks + lb * 16);
      gll16(Vtg + ((size_t)bh * DK_ + r) * L_ + c16 * 8, (char*)Vs + lb * 16);
    }
    VMCNT(0);
    BARRIER();

    f32x4 acco[2][4] = {};          // [half][d-block]; row q = l4*4+rg
    float m[2] = {-1e30f, -1e30f};  // per-lane: q = l15 (per half)
    float l[2] = {0.f, 0.f};

    for (int t = 0; t < nt; ++t) {
      const int cur = t & 1;
      const int kv0 = t * 64;
      const char* Kc = (const char*)Ks + cur * 8192;
      const char* Vc = (const char*)Vs + cur * 8192;

      if (t + 1 < nt) {
        const int nb = (t + 1) & 1, nkv = (t + 1) * 64;
#pragma unroll
        for (int i = 0; i < 2; ++i) {
          int lb = i * 256 + tid;
          int r = lb >> 3, c16 = (lb & 7) ^ (r & 7);
          gll16(Kg + ((size_t)bh * L_ + nkv + r) * DK_ + c16 * 8,
                (char*)Ks + nb * 8192 + lb * 16);
          gll16(Vtg + ((size_t)bh * DK_ + r) * L_ + nkv + c16 * 8,
                (char*)Vs + nb * 8192 + lb * 16);
        }
        VMCNT(4);
      } else {
        VMCNT(0);
      }
      BARRIER();

      if (kv0 <= q0w + 31) {  // wave has unmasked rows in this tile
        // ---- S^T = K Q^T : s[mi][ni][rg] = S^T[kv=ni*16+l4*4+rg][q=l15]
        f32x4 s[2][4] = {};
        __builtin_amdgcn_s_setprio(1);
#pragma unroll
        for (int kk = 0; kk < 2; ++kk)
#pragma unroll
          for (int ni = 0; ni < 4; ++ni) {
            int r = ni * 16 + l15;
            int ch = (kk * 4 + l4) ^ (r & 7);
            bf16x8 kf = *(const bf16x8*)(Kc + r * 128 + ch * 16);
#pragma unroll
            for (int mi = 0; mi < 2; ++mi)
              s[mi][ni] = MFMA(kf, qf[mi][kk], s[mi][ni]);
          }
        __builtin_amdgcn_s_setprio(0);

        if (kv0 + 63 > q0w) {  // diagonal band: mask kv > q
#pragma unroll
          for (int mi = 0; mi < 2; ++mi) {
            int qg_ = q0w + mi * 16 + l15;
#pragma unroll
            for (int ni = 0; ni < 4; ++ni) {
              int kvg = kv0 + ni * 16 + l4 * 4;
#pragma unroll
              for (int rg = 0; rg < 4; ++rg)
                if (kvg + rg > qg_) s[mi][ni][rg] = -1e30f;
            }
          }
        }

        // ---- row max + defer-max rescale
        float mx[2];
#pragma unroll
        for (int mi = 0; mi < 2; ++mi) {
          float v = fmaxf(fmaxf(fmaxf(s[mi][0][0], s[mi][0][1]),
                                fmaxf(s[mi][0][2], s[mi][0][3])),
                          fmaxf(fmaxf(s[mi][1][0], s[mi][1][1]),
                                fmaxf(s[mi][1][2], s[mi][1][3])));
          v = fmaxf(v, fmaxf(fmaxf(fmaxf(s[mi][2][0], s[mi][2][1]),
                                   fmaxf(s[mi][2][2], s[mi][2][3])),
                             fmaxf(fmaxf(s[mi][3][0], s[mi][3][1]),
                                   fmaxf(s[mi][3][2], s[mi][3][3]))));
          v = fmaxf(v, __shfl_xor(v, 16));
          v = fmaxf(v, __shfl_xor(v, 32));
          mx[mi] = v;
        }
        float grow = fmaxf(mx[0] - m[0], mx[1] - m[1]);
        if (__any(grow > 11.0f)) {
#pragma unroll
          for (int mi = 0; mi < 2; ++mi) {
            float mn = fmaxf(m[mi], mx[mi]);
            float sc = __builtin_amdgcn_exp2f(m[mi] - mn);
            m[mi] = mn;
            l[mi] *= sc;
#pragma unroll
            for (int rg = 0; rg < 4; ++rg) {
              float scq = __shfl(sc, l4 * 4 + rg);
              acco[mi][0][rg] *= scq; acco[mi][1][rg] *= scq;
              acco[mi][2][rg] *= scq; acco[mi][3][rg] *= scq;
            }
          }
        }

        // ---- P = exp2(S^T - m), pack bf16 pairs (kv ascending)
        uint32_t pk[2][4][2];
#pragma unroll
        for (int mi = 0; mi < 2; ++mi)
#pragma unroll
          for (int ni = 0; ni < 4; ++ni) {
            float p0 = __builtin_amdgcn_exp2f(s[mi][ni][0] - m[mi]);
            float p1 = __builtin_amdgcn_exp2f(s[mi][ni][1] - m[mi]);
            float p2 = __builtin_amdgcn_exp2f(s[mi][ni][2] - m[mi]);
            float p3 = __builtin_amdgcn_exp2f(s[mi][ni][3] - m[mi]);
            l[mi] += (p0 + p1) + (p2 + p3);
            asm("v_cvt_pk_bf16_f32 %0, %1, %2" : "=v"(pk[mi][ni][0]) : "v"(p0), "v"(p1));
            asm("v_cvt_pk_bf16_f32 %0, %1, %2" : "=v"(pk[mi][ni][1]) : "v"(p2), "v"(p3));
          }

        // ---- O += P V : pk words ARE the A-frag (V kv-cols pre-permuted)
        __builtin_amdgcn_s_setprio(1);
#pragma unroll
        for (int kk = 0; kk < 2; ++kk) {
          union { uint32_t wd[4]; bf16x8 v; } u[2];
#pragma unroll
          for (int mi = 0; mi < 2; ++mi) {
            u[mi].wd[0] = pk[mi][2 * kk][0];
            u[mi].wd[1] = pk[mi][2 * kk][1];
            u[mi].wd[2] = pk[mi][2 * kk + 1][0];
            u[mi].wd[3] = pk[mi][2 * kk + 1][1];
          }
#pragma unroll
          for (int ni = 0; ni < 4; ++ni) {
            int r = ni * 16 + l15;
            int ch = (kk * 4 + l4) ^ (r & 7);
            bf16x8 vf = *(const bf16x8*)(Vc + r * 128 + ch * 16);
#pragma unroll
            for (int mi = 0; mi < 2; ++mi)
              acco[mi][ni] = MFMA(u[mi].v, vf, acco[mi][ni]);
          }
        }
        __builtin_amdgcn_s_setprio(0);
      }  // active wave

      BARRIER();  // all waves done with buf[cur]
    }

    // ---- epilogue
#pragma unroll
    for (int mi = 0; mi < 2; ++mi) {
      float ls = l[mi];
      ls += __shfl_xor(ls, 16);
      ls += __shfl_xor(ls, 32);
      float linv = 1.0f / ls;
#pragma unroll
      for (int rg = 0; rg < 4; ++rg) {
        float lq = __shfl(linv, l4 * 4 + rg);
        int q = q0w + mi * 16 + l4 * 4 + rg;
#pragma unroll
        for (int ni = 0; ni < 4; ++ni) {
          int d = ni * 16 + l15;
          Ao[((size_t)b * L_ + q) * D_ + h * DK_ + d] = f2bf(acco[mi][ni][rg] * lq);
        }
      }
    }
  }  // seg
}

// ---------------- launch ----------------

extern "C" void kernel_launch(void* const* d_in, const int* in_sizes, int n_in,
                              void* d_out, int out_size, void* d_ws, size_t ws_size,
                              hipStream_t stream) {
  const float* x = (const float*)d_in[0];
  const float* W_qkv = (const float*)d_in[1];
  const float* b_qkv = (const float*)d_in[2];
  const float* W_out = (const float*)d_in[3];
  const float* b_out = (const float*)d_in[4];
  float* out = (float*)d_out;

  char* ws = (char*)d_ws;
  bfu* xb     = (bfu*)(ws);                    // 8192*1024*2   = 16,777,216
  bfu* Wqkv_t = (bfu*)(ws + 16777216);         // 3072*1024*2   =  6,291,456
  bfu* Wout_t = (bfu*)(ws + 23068672);         // 1024*1024*2   =  2,097,152
  bfu* Qg     = (bfu*)(ws + 25165824);         // 16,777,216
  bfu* Kg     = (bfu*)(ws + 41943040);         // 16,777,216
  bfu* Vtg    = (bfu*)(ws + 58720256);         // 16,777,216
  bfu* Ao     = (bfu*)(ws + 75497472);         // 16,777,216  (total ~92.3 MB)

  cast_x<<<8192, 256, 0, stream>>>(x, xb, 2097152);
  transpose_cast<<<dim3(96, 32), dim3(32, 8), 0, stream>>>(W_qkv, Wqkv_t, 1024, 3072);
  transpose_cast<<<dim3(32, 32), dim3(32, 8), 0, stream>>>(W_out, Wout_t, 1024, 1024);

  gemm8<0, 128, 128, 4, 2><<<1536, 512, 0, stream>>>(xb, Wqkv_t, b_qkv, Qg, Kg,
                                                     Vtg, nullptr, 8192, 3072, 1024);
  attn<<<512, 256, 0, stream>>>(Qg, Kg, Vtg, Ao);
  gemm8<1, 128, 128, 4, 2><<<512, 512, 0, stream>>>(Ao, Wout_t, b_out, nullptr,
                                                    nullptr, nullptr, out, 8192,
                                                    1024, 1024);
}

// Round 9
// 181.737 us; speedup vs baseline: 1.0004x; 1.0004x over previous
//
#include <hip/hip_runtime.h>
#include <stdint.h>

#define B_ 4
#define L_ 2048
#define D_ 1024
#define H_ 16
#define DK_ 64

typedef __attribute__((ext_vector_type(8))) short bf16x8;
typedef __attribute__((ext_vector_type(4))) float f32x4;
typedef unsigned short bfu;   // raw bf16 storage

#define MFMA(a, b, c) __builtin_amdgcn_mfma_f32_16x16x32_bf16((a), (b), (c), 0, 0, 0)

__device__ __forceinline__ unsigned short f2bf(float f) {
  union { float f; unsigned int u; } v; v.f = f;
  unsigned int u = v.u;
  return (unsigned short)((u + 0x7fffu + ((u >> 16) & 1u)) >> 16);  // RNE
}

__device__ __forceinline__ void gll16(const void* g, void* l) {
  __builtin_amdgcn_global_load_lds(
      (const __attribute__((address_space(1))) void*)g,
      (__attribute__((address_space(3))) void*)l, 16, 0, 0);
}

#define VMCNT(n_) asm volatile("s_waitcnt vmcnt(" #n_ ")" ::: "memory")
#define BARRIER() asm volatile("s_barrier" ::: "memory")

// ---------------- prep kernels ----------------

__global__ __launch_bounds__(256) void cast_x(const float* __restrict__ in,
                                              bfu* __restrict__ out, int n4) {
  int i = blockIdx.x * 256 + threadIdx.x;
  if (i >= n4) return;
  float4 v = ((const float4*)in)[i];
  ushort4 o;
  o.x = f2bf(v.x); o.y = f2bf(v.y); o.z = f2bf(v.z); o.w = f2bf(v.w);
  ((ushort4*)out)[i] = o;
}

// in[R][C] fp32 -> out[C][R] bf16
__global__ void transpose_cast(const float* __restrict__ in, bfu* __restrict__ out,
                               int R, int C) {
  __shared__ float tile[32][33];
  int c0 = blockIdx.x * 32, r0 = blockIdx.y * 32;
  int tx = threadIdx.x, ty = threadIdx.y;  // 32 x 8
#pragma unroll
  for (int i = ty; i < 32; i += 8)
    tile[i][tx] = in[(size_t)(r0 + i) * C + c0 + tx];
  __syncthreads();
#pragma unroll
  for (int i = ty; i < 32; i += 8)
    out[(size_t)(c0 + i) * R + r0 + tx] = f2bf(tile[tx][i]);
}

// ---------------- single-buffered 2-barrier BT GEMM (m103 structure) -------
// C[M][N] = A[M][K] * Bt[N][K]^T. TH = WM*WN*64 threads, per-wave 64x64
// (acc[4][4]). BK=64, SINGLE LDS buffer (BM=128,BN=256 -> 48KB -> 2 blk/CU).
// Loop: sync; stage(t); sync(+compiler vmcnt0); compute(t). Inter-block
// overlap (2-3 blocks/CU) hides the barrier drain (m114 mechanism).
// Supertile swizzle: each XCD owns an 8-m-tile band (A L2-resident), sweeps n.
// EPI 0: scatter Q (scaled log2e/8), K, V (sigma^-1-permuted transpose via
// LDS, BN/128 passes). EPI 1: fp32 out += bias.

template <int EPI, int BM, int BN, int WM, int WN, int OCC>
__global__ __launch_bounds__(WM * WN * 64, OCC) void gemm_s(
    const bfu* __restrict__ A, const bfu* __restrict__ Bt,
    const float* __restrict__ bias, bfu* __restrict__ Qg, bfu* __restrict__ Kg,
    bfu* __restrict__ Vtg, float* __restrict__ Out, int M, int N, int K) {
  __shared__ __align__(16) bfu LDSb[(BM + BN) * 64];
  constexpr int TH = WM * WN * 64;
  constexpr int RM = BM / WM, RN = BN / WN;
  static_assert(RM == 64 && RN == 64, "per-wave tile is 64x64");

  const int tid = threadIdx.x;
  const int lane = tid & 63;
  const int w = tid >> 6;
  const int wm = w / WN, wn = w % WN;
  const int l15 = lane & 15, l4 = lane >> 4;

  // XCD-contiguous + supertile: XCD x owns m-tiles [8x, 8x+8), sweeps all n.
  const int nwg = gridDim.x;
  const int cpx = nwg >> 3;
  const int bid = (int)blockIdx.x;
  const int swz = (bid & 7) * cpx + (bid >> 3);
  const int NTt = N / BN;
  const int m0 = ((swz & 7) + 8 * (swz / (8 * NTt))) * BM;
  const int n0 = ((swz >> 3) % NTt) * BN;

  auto stageA = [&](int t) {
    char* lb = (char*)LDSb;
#pragma unroll
    for (int j = 0; j < BM * 8 / TH; ++j) {
      int idx = j * TH + tid;
      int row = idx >> 3, c16p = idx & 7;
      int c16 = c16p ^ (row & 7);
      gll16(A + (size_t)(m0 + row) * K + t * 64 + c16 * 8,
            lb + row * 128 + c16p * 16);
    }
  };
  auto stageB = [&](int t) {
    char* lb = (char*)(LDSb + BM * 64);
#pragma unroll
    for (int j = 0; j < BN * 8 / TH; ++j) {
      int idx = j * TH + tid;
      int row = idx >> 3, c16p = idx & 7;
      int c16 = c16p ^ (row & 7);
      gll16(Bt + (size_t)(n0 + row) * K + t * 64 + c16 * 8,
            lb + row * 128 + c16p * 16);
    }
  };

  f32x4 acc[4][4] = {};
  bf16x8 af[4][2], bfh[2][2];

  auto lda = [&]() {
    const char* base = (const char*)LDSb;
#pragma unroll
    for (int mi = 0; mi < 4; ++mi)
#pragma unroll
      for (int kk = 0; kk < 2; ++kk) {
        int row = wm * RM + mi * 16 + l15;
        int ch = (kk * 4 + l4) ^ (row & 7);
        af[mi][kk] = *(const bf16x8*)(base + row * 128 + ch * 16);
      }
  };
  auto ldb = [&](int half) {
    const char* base = (const char*)(LDSb + BM * 64);
#pragma unroll
    for (int ni = 0; ni < 2; ++ni)
#pragma unroll
      for (int kk = 0; kk < 2; ++kk) {
        int row = wn * RN + half * 32 + ni * 16 + l15;
        int ch = (kk * 4 + l4) ^ (row & 7);
        bfh[ni][kk] = *(const bf16x8*)(base + row * 128 + ch * 16);
      }
  };
  auto mmh = [&](int half) {
    __builtin_amdgcn_s_setprio(1);
#pragma unroll
    for (int mi = 0; mi < 4; ++mi)
#pragma unroll
      for (int ni = 0; ni < 2; ++ni)
#pragma unroll
        for (int kk = 0; kk < 2; ++kk)
          acc[mi][half * 2 + ni] =
              MFMA(af[mi][kk], bfh[ni][kk], acc[mi][half * 2 + ni]);
    __builtin_amdgcn_s_setprio(0);
  };

  const int NT = K >> 6;
  for (int t = 0; t < NT; ++t) {
    __syncthreads();            // all reads of tile t-1 done
    stageA(t); stageB(t);
    __syncthreads();            // compiler drains vmcnt before barrier
    lda();
    ldb(0); mmh(0);
    ldb(1); mmh(1);
  }

  // ---- epilogue: C/D layout col = lane&15, row = (lane>>4)*4 + reg
  if constexpr (EPI == 1) {
#pragma unroll
    for (int ni = 0; ni < 4; ++ni) {
      int gn = n0 + wn * RN + ni * 16 + l15;
      float bv = bias[gn];
#pragma unroll
      for (int mi = 0; mi < 4; ++mi)
#pragma unroll
        for (int rg = 0; rg < 4; ++rg) {
          int gm = m0 + wm * RM + mi * 16 + l4 * 4 + rg;
          Out[(size_t)gm * N + gn] = acc[mi][ni][rg] + bv;
        }
    }
  } else {
    const int sec = n0 >> 10;  // 1024-aligned sections: 0 Q, 1 K, 2 V
    if (sec < 2) {
      bfu* dst = (sec == 0) ? Qg : Kg;
      const float scale = (sec == 0) ? 0.18033688011112042f : 1.0f;  // log2e/8
#pragma unroll
      for (int ni = 0; ni < 4; ++ni) {
        int gn = n0 + wn * RN + ni * 16 + l15;
        int rem = gn & 1023;
        int hh = rem >> 6, dk = rem & 63;
        float bv = bias[gn];
#pragma unroll
        for (int mi = 0; mi < 4; ++mi)
#pragma unroll
          for (int rg = 0; rg < 4; ++rg) {
            int gm = m0 + wm * RM + mi * 16 + l4 * 4 + rg;
            int bb = gm >> 11, ll = gm & 2047;
            dst[(((size_t)(bb * H_ + hh)) * L_ + ll) * DK_ + dk] =
                f2bf((acc[mi][ni][rg] + bv) * scale);
          }
      }
    } else {
      // V: sigma^-1-permuted transpose via LDS, BN/128 passes of 128 n-rows
      __syncthreads();
#pragma unroll
      for (int pass = 0; pass < BN / 128; ++pass) {
        if (wn * RN >= pass * 128 && wn * RN < pass * 128 + 128) {
#pragma unroll
          for (int ni = 0; ni < 4; ++ni) {
            int n_local = wn * RN + ni * 16 + l15;
            int n_rel = n_local - pass * 128;
            int gn = n0 + n_local;
            float bv = bias[gn];
            int swzn = (n_rel & 7) << 4;
#pragma unroll
            for (int mi = 0; mi < 4; ++mi) {
              int m_base = wm * RM + mi * 16 + l4 * 4;
              int k6 = m_base & 63;
              int p0 = (m_base & ~63) |
                       ((k6 & 32) | (((k6 >> 2) & 3) << 3) | (((k6 >> 4) & 1) << 2));
              float v0 = acc[mi][ni][0] + bv, v1 = acc[mi][ni][1] + bv;
              float v2 = acc[mi][ni][2] + bv, v3 = acc[mi][ni][3] + bv;
              uint32_t w01, w23;
              asm("v_cvt_pk_bf16_f32 %0, %1, %2" : "=v"(w01) : "v"(v0), "v"(v1));
              asm("v_cvt_pk_bf16_f32 %0, %1, %2" : "=v"(w23) : "v"(v2), "v"(v3));
              *(uint32_t*)((char*)LDSb + n_rel * (BM * 2) + ((2 * p0) ^ swzn)) = w01;
              *(uint32_t*)((char*)LDSb + n_rel * (BM * 2) + ((2 * p0 + 4) ^ swzn)) = w23;
            }
          }
        }
        __syncthreads();
        // readers: TH threads, 4 per n-row (128 rows), 4 x 16B chunks each
        if (TH >= 512 || true) {
          int n = tid >> 2;     // [0,128) for TH=512
          if (n < 128) {
            int cb = (tid & 3) * 4;
            int gnn = n0 + pass * 128 + n;
            int hh = (gnn >> 6) & 15, dk = gnn & 63;
            size_t rowbase =
                (((size_t)((m0 >> 11) * H_ + hh)) * DK_ + dk) * L_ + (m0 & 2047);
#pragma unroll
            for (int j = 0; j < 4; ++j) {
              int ch = cb + j;
              bf16x8 vv = *(const bf16x8*)((char*)LDSb + n * (BM * 2) +
                                           ((ch * 16) ^ ((n & 7) << 4)));
              *(bf16x8*)(Vtg + rowbase + ch * 8) = vv;
            }
          }
        }
        __syncthreads();
      }
    }
  }
}

// ---------------- flash attention v3 (causal) ----------------
// 512 blocks; xcd = hid&7, 8 bh per XCD (K/V L2 locality). Block handles
// 128-row q-superblocks {p, 15-p} (34 KV tiles, perfect balance). 4 waves;
// wave owns 32 q rows (2 x 16). Q loaded directly to registers (no Q LDS).
// S^T = mfma(K,Q): lane owns softmax stats of one q-row per half. V stored
// sigma-permuted so packed P words ARE the PV A-fragment (no cross-lane).

__global__ __launch_bounds__(256, 3) void attn(const bfu* __restrict__ Qg,
                                               const bfu* __restrict__ Kg,
                                               const bfu* __restrict__ Vtg,
                                               bfu* __restrict__ Ao) {
  __shared__ __align__(16) bfu Ks[2 * 64 * 64];
  __shared__ __align__(16) bfu Vs[2 * 64 * 64];

  const int tid = threadIdx.x;
  const int lane = tid & 63;
  const int w = tid >> 6;
  const int l15 = lane & 15, l4 = lane >> 4;

  const int hid = blockIdx.x;            // 512 blocks
  const int xcd = hid & 7, slot = hid >> 3;
  const int bh = xcd * 8 + (slot >> 3);  // 8 bh per XCD
  const int p = slot & 7;
  const int b = bh >> 4, h = bh & 15;

  for (int seg = 0; seg < 2; ++seg) {
    const int qb = (seg == 0) ? p : 15 - p;   // 128-row superblock
    const int q0 = qb * 128;
    const int nt = 2 * qb + 2;
    const int q0w = q0 + w * 32;              // wave's first q row

    // ---- Q fragments straight from global (Qg pre-scaled by log2e/8)
    bf16x8 qf[2][2];
#pragma unroll
    for (int mi = 0; mi < 2; ++mi)
#pragma unroll
      for (int kk = 0; kk < 2; ++kk)
        qf[mi][kk] = *(const bf16x8*)(
            Qg + ((size_t)bh * L_ + q0w + mi * 16 + l15) * DK_ + kk * 32 + l4 * 8);

    // ---- stage KV tile 0 (buffer 0)
#pragma unroll
    for (int i = 0; i < 2; ++i) {
      int lb = i * 256 + tid;
      int r = lb >> 3, c16 = (lb & 7) ^ (r & 7);
      gll16(Kg + ((size_t)bh * L_ + r) * DK_ + c16 * 8, (char*)Ks + lb * 16);
      gll16(Vtg + ((size_t)bh * DK_ + r) * L_ + c16 * 8, (char*)Vs + lb * 16);
    }
    VMCNT(0);
    BARRIER();

    f32x4 acco[2][4] = {};          // [half][d-block]; row q = l4*4+rg
    float m[2] = {-1e30f, -1e30f};  // per-lane: q = l15 (per half)
    float l[2] = {0.f, 0.f};

    for (int t = 0; t < nt; ++t) {
      const int cur = t & 1;
      const int kv0 = t * 64;
      const char* Kc = (const char*)Ks + cur * 8192;
      const char* Vc = (const char*)Vs + cur * 8192;

      if (t + 1 < nt) {
        const int nb = (t + 1) & 1, nkv = (t + 1) * 64;
#pragma unroll
        for (int i = 0; i < 2; ++i) {
          int lb = i * 256 + tid;
          int r = lb >> 3, c16 = (lb & 7) ^ (r & 7);
          gll16(Kg + ((size_t)bh * L_ + nkv + r) * DK_ + c16 * 8,
                (char*)Ks + nb * 8192 + lb * 16);
          gll16(Vtg + ((size_t)bh * DK_ + r) * L_ + nkv + c16 * 8,
                (char*)Vs + nb * 8192 + lb * 16);
        }
        VMCNT(4);
      } else {
        VMCNT(0);
      }
      BARRIER();

      if (kv0 <= q0w + 31) {  // wave has unmasked rows in this tile
        // ---- S^T = K Q^T : s[mi][ni][rg] = S^T[kv=ni*16+l4*4+rg][q=l15]
        f32x4 s[2][4] = {};
        __builtin_amdgcn_s_setprio(1);
#pragma unroll
        for (int kk = 0; kk < 2; ++kk)
#pragma unroll
          for (int ni = 0; ni < 4; ++ni) {
            int r = ni * 16 + l15;
            int ch = (kk * 4 + l4) ^ (r & 7);
            bf16x8 kf = *(const bf16x8*)(Kc + r * 128 + ch * 16);
#pragma unroll
            for (int mi = 0; mi < 2; ++mi)
              s[mi][ni] = MFMA(kf, qf[mi][kk], s[mi][ni]);
          }
        __builtin_amdgcn_s_setprio(0);

        if (kv0 + 63 > q0w) {  // diagonal band: mask kv > q
#pragma unroll
          for (int mi = 0; mi < 2; ++mi) {
            int qg_ = q0w + mi * 16 + l15;
#pragma unroll
            for (int ni = 0; ni < 4; ++ni) {
              int kvg = kv0 + ni * 16 + l4 * 4;
#pragma unroll
              for (int rg = 0; rg < 4; ++rg)
                if (kvg + rg > qg_) s[mi][ni][rg] = -1e30f;
            }
          }
        }

        // ---- row max + defer-max rescale
        float mx[2];
#pragma unroll
        for (int mi = 0; mi < 2; ++mi) {
          float v = fmaxf(fmaxf(fmaxf(s[mi][0][0], s[mi][0][1]),
                                fmaxf(s[mi][0][2], s[mi][0][3])),
                          fmaxf(fmaxf(s[mi][1][0], s[mi][1][1]),
                                fmaxf(s[mi][1][2], s[mi][1][3])));
          v = fmaxf(v, fmaxf(fmaxf(fmaxf(s[mi][2][0], s[mi][2][1]),
                                   fmaxf(s[mi][2][2], s[mi][2][3])),
                             fmaxf(fmaxf(s[mi][3][0], s[mi][3][1]),
                                   fmaxf(s[mi][3][2], s[mi][3][3]))));
          v = fmaxf(v, __shfl_xor(v, 16));
          v = fmaxf(v, __shfl_xor(v, 32));
          mx[mi] = v;
        }
        float grow = fmaxf(mx[0] - m[0], mx[1] - m[1]);
        if (__any(grow > 11.0f)) {
#pragma unroll
          for (int mi = 0; mi < 2; ++mi) {
            float mn = fmaxf(m[mi], mx[mi]);
            float sc = __builtin_amdgcn_exp2f(m[mi] - mn);
            m[mi] = mn;
            l[mi] *= sc;
#pragma unroll
            for (int rg = 0; rg < 4; ++rg) {
              float scq = __shfl(sc, l4 * 4 + rg);
              acco[mi][0][rg] *= scq; acco[mi][1][rg] *= scq;
              acco[mi][2][rg] *= scq; acco[mi][3][rg] *= scq;
            }
          }
        }

        // ---- P = exp2(S^T - m), pack bf16 pairs (kv ascending)
        uint32_t pk[2][4][2];
#pragma unroll
        for (int mi = 0; mi < 2; ++mi)
#pragma unroll
          for (int ni = 0; ni < 4; ++ni) {
            float p0 = __builtin_amdgcn_exp2f(s[mi][ni][0] - m[mi]);
            float p1 = __builtin_amdgcn_exp2f(s[mi][ni][1] - m[mi]);
            float p2 = __builtin_amdgcn_exp2f(s[mi][ni][2] - m[mi]);
            float p3 = __builtin_amdgcn_exp2f(s[mi][ni][3] - m[mi]);
            l[mi] += (p0 + p1) + (p2 + p3);
            asm("v_cvt_pk_bf16_f32 %0, %1, %2" : "=v"(pk[mi][ni][0]) : "v"(p0), "v"(p1));
            asm("v_cvt_pk_bf16_f32 %0, %1, %2" : "=v"(pk[mi][ni][1]) : "v"(p2), "v"(p3));
          }

        // ---- O += P V : pk words ARE the A-frag (V kv-cols pre-permuted)
        __builtin_amdgcn_s_setprio(1);
#pragma unroll
        for (int kk = 0; kk < 2; ++kk) {
          union { uint32_t wd[4]; bf16x8 v; } u[2];
#pragma unroll
          for (int mi = 0; mi < 2; ++mi) {
            u[mi].wd[0] = pk[mi][2 * kk][0];
            u[mi].wd[1] = pk[mi][2 * kk][1];
            u[mi].wd[2] = pk[mi][2 * kk + 1][0];
            u[mi].wd[3] = pk[mi][2 * kk + 1][1];
          }
#pragma unroll
          for (int ni = 0; ni < 4; ++ni) {
            int r = ni * 16 + l15;
            int ch = (kk * 4 + l4) ^ (r & 7);
            bf16x8 vf = *(const bf16x8*)(Vc + r * 128 + ch * 16);
#pragma unroll
            for (int mi = 0; mi < 2; ++mi)
              acco[mi][ni] = MFMA(u[mi].v, vf, acco[mi][ni]);
          }
        }
        __builtin_amdgcn_s_setprio(0);
      }  // active wave

      BARRIER();  // all waves done with buf[cur]
    }

    // ---- epilogue
#pragma unroll
    for (int mi = 0; mi < 2; ++mi) {
      float ls = l[mi];
      ls += __shfl_xor(ls, 16);
      ls += __shfl_xor(ls, 32);
      float linv = 1.0f / ls;
#pragma unroll
      for (int rg = 0; rg < 4; ++rg) {
        float lq = __shfl(linv, l4 * 4 + rg);
        int q = q0w + mi * 16 + l4 * 4 + rg;
#pragma unroll
        for (int ni = 0; ni < 4; ++ni) {
          int d = ni * 16 + l15;
          Ao[((size_t)b * L_ + q) * D_ + h * DK_ + d] = f2bf(acco[mi][ni][rg] * lq);
        }
      }
    }
  }  // seg
}

// ---------------- launch ----------------

extern "C" void kernel_launch(void* const* d_in, const int* in_sizes, int n_in,
                              void* d_out, int out_size, void* d_ws, size_t ws_size,
                              hipStream_t stream) {
  const float* x = (const float*)d_in[0];
  const float* W_qkv = (const float*)d_in[1];
  const float* b_qkv = (const float*)d_in[2];
  const float* W_out = (const float*)d_in[3];
  const float* b_out = (const float*)d_in[4];
  float* out = (float*)d_out;

  char* ws = (char*)d_ws;
  bfu* xb     = (bfu*)(ws);                    // 8192*1024*2   = 16,777,216
  bfu* Wqkv_t = (bfu*)(ws + 16777216);         // 3072*1024*2   =  6,291,456
  bfu* Wout_t = (bfu*)(ws + 23068672);         // 1024*1024*2   =  2,097,152
  bfu* Qg     = (bfu*)(ws + 25165824);         // 16,777,216
  bfu* Kg     = (bfu*)(ws + 41943040);         // 16,777,216
  bfu* Vtg    = (bfu*)(ws + 58720256);         // 16,777,216
  bfu* Ao     = (bfu*)(ws + 75497472);         // 16,777,216  (total ~92.3 MB)

  cast_x<<<8192, 256, 0, stream>>>(x, xb, 2097152);
  transpose_cast<<<dim3(96, 32), dim3(32, 8), 0, stream>>>(W_qkv, Wqkv_t, 1024, 3072);
  transpose_cast<<<dim3(32, 32), dim3(32, 8), 0, stream>>>(W_out, Wout_t, 1024, 1024);

  // gemm0: 128x256 tiles, grid 64m x 12n = 768, 512 thr, 2 blk/CU
  gemm_s<0, 128, 256, 2, 4, 4><<<768, 512, 0, stream>>>(
      xb, Wqkv_t, b_qkv, Qg, Kg, Vtg, nullptr, 8192, 3072, 1024);
  attn<<<512, 256, 0, stream>>>(Qg, Kg, Vtg, Ao);
  // gemm1: 128x128 tiles, grid 64m x 8n = 512, 256 thr, 3 blk/CU
  gemm_s<1, 128, 128, 2, 2, 3><<<512, 256, 0, stream>>>(
      Ao, Wout_t, b_out, nullptr, nullptr, nullptr, out, 8192, 1024, 1024);
}

// Round 10
// 175.005 us; speedup vs baseline: 1.0389x; 1.0385x over previous
//
#include <hip/hip_runtime.h>
#include <stdint.h>

#define B_ 4
#define L_ 2048
#define D_ 1024
#define H_ 16
#define DK_ 64

typedef __attribute__((ext_vector_type(8))) short bf16x8;
typedef __attribute__((ext_vector_type(4))) float f32x4;
typedef unsigned short bfu;   // raw bf16 storage

#define MFMA(a, b, c) __builtin_amdgcn_mfma_f32_16x16x32_bf16((a), (b), (c), 0, 0, 0)

__device__ __forceinline__ unsigned short f2bf(float f) {
  union { float f; unsigned int u; } v; v.f = f;
  unsigned int u = v.u;
  return (unsigned short)((u + 0x7fffu + ((u >> 16) & 1u)) >> 16);  // RNE
}

__device__ __forceinline__ void gll16(const void* g, void* l) {
  __builtin_amdgcn_global_load_lds(
      (const __attribute__((address_space(1))) void*)g,
      (__attribute__((address_space(3))) void*)l, 16, 0, 0);
}

#define VMCNT(n_) asm volatile("s_waitcnt vmcnt(" #n_ ")" ::: "memory")
#define BARRIER() asm volatile("s_barrier" ::: "memory")

// ---------------- prep kernels ----------------

__global__ __launch_bounds__(256) void cast_x(const float* __restrict__ in,
                                              bfu* __restrict__ out, int n4) {
  int i = blockIdx.x * 256 + threadIdx.x;
  if (i >= n4) return;
  float4 v = ((const float4*)in)[i];
  ushort4 o;
  o.x = f2bf(v.x); o.y = f2bf(v.y); o.z = f2bf(v.z); o.w = f2bf(v.w);
  ((ushort4*)out)[i] = o;
}

// in[R][C] fp32 -> out[C][R] bf16
__global__ void transpose_cast(const float* __restrict__ in, bfu* __restrict__ out,
                               int R, int C) {
  __shared__ float tile[32][33];
  int c0 = blockIdx.x * 32, r0 = blockIdx.y * 32;
  int tx = threadIdx.x, ty = threadIdx.y;  // 32 x 8
#pragma unroll
  for (int i = ty; i < 32; i += 8)
    tile[i][tx] = in[(size_t)(r0 + i) * C + c0 + tx];
  __syncthreads();
#pragma unroll
  for (int i = ty; i < 32; i += 8)
    out[(size_t)(c0 + i) * R + r0 + tx] = f2bf(tile[tx][i]);
}

// ------- wide-wave single-buffered BT GEMM (per-wave 128x64, m103 loop) -----
// C[M][N] = A[M][K] * Bt[N][K]^T. WN waves (WM=1): per-wave output BM x 64
// with BM=128 -> acc[8][4] (128 VGPR), A preloaded to regs (16 b128), B per
// half (4 b128) => 24 ds_read per 64 MFMA (HK ratio, LDS ceiling ~89%).
// Single LDS buffer (BM+BN)*128B: gemm0 48KB -> 2 blk/CU; latency hidden by
// the peer block (m114). 2-barrier loop. Supertile swizzle: each XCD owns an
// 8-m-tile band, sweeps n (A L2-resident). EPI 0: scatter Q (scaled log2e/8),
// K, V (sigma^-1-permuted transpose via LDS). EPI 1: fp32 out += bias.

template <int EPI, int BM, int BN, int WN>
__global__ __launch_bounds__(WN * 64, 2) void gemm_w(
    const bfu* __restrict__ A, const bfu* __restrict__ Bt,
    const float* __restrict__ bias, bfu* __restrict__ Qg, bfu* __restrict__ Kg,
    bfu* __restrict__ Vtg, float* __restrict__ Out, int M, int N, int K) {
  __shared__ __align__(16) bfu LDSb[(BM + BN) * 64];
  constexpr int TH = WN * 64;
  constexpr int MH = BM / 16;            // 8 A-frag rows-blocks
  static_assert(BN / WN == 64, "per-wave N is 64");

  const int tid = threadIdx.x;
  const int lane = tid & 63;
  const int wn = tid >> 6;
  const int l15 = lane & 15, l4 = lane >> 4;

  // XCD-contiguous supertile: XCD x owns m-tiles [8x,8x+8), sweeps all n.
  const int nwg = gridDim.x;
  const int cpx = nwg >> 3;
  const int bid = (int)blockIdx.x;
  const int swz = (bid & 7) * cpx + (bid >> 3);
  const int NTt = N / BN;
  const int m0 = ((swz & 7) + 8 * (swz / (8 * NTt))) * BM;
  const int n0 = ((swz >> 3) % NTt) * BN;

  auto stageA = [&](int t) {
    char* lb = (char*)LDSb;
#pragma unroll
    for (int j = 0; j < BM * 8 / TH; ++j) {
      int idx = j * TH + tid;
      int row = idx >> 3, c16p = idx & 7;
      int c16 = c16p ^ (row & 7);
      gll16(A + (size_t)(m0 + row) * K + t * 64 + c16 * 8,
            lb + row * 128 + c16p * 16);
    }
  };
  auto stageB = [&](int t) {
    char* lb = (char*)(LDSb + BM * 64);
#pragma unroll
    for (int j = 0; j < BN * 8 / TH; ++j) {
      int idx = j * TH + tid;
      int row = idx >> 3, c16p = idx & 7;
      int c16 = c16p ^ (row & 7);
      gll16(Bt + (size_t)(n0 + row) * K + t * 64 + c16 * 8,
            lb + row * 128 + c16p * 16);
    }
  };

  f32x4 acc[MH][4] = {};
  bf16x8 af[MH][2], bh[2][2];

  auto lda_all = [&]() {
    const char* base = (const char*)LDSb;
#pragma unroll
    for (int mi = 0; mi < MH; ++mi)
#pragma unroll
      for (int kk = 0; kk < 2; ++kk) {
        int row = mi * 16 + l15;
        int ch = (kk * 4 + l4) ^ (row & 7);
        af[mi][kk] = *(const bf16x8*)(base + row * 128 + ch * 16);
      }
  };
  auto ldb = [&](int half) {
    const char* base = (const char*)(LDSb + BM * 64);
#pragma unroll
    for (int ni = 0; ni < 2; ++ni)
#pragma unroll
      for (int kk = 0; kk < 2; ++kk) {
        int row = wn * 64 + half * 32 + ni * 16 + l15;
        int ch = (kk * 4 + l4) ^ (row & 7);
        bh[ni][kk] = *(const bf16x8*)(base + row * 128 + ch * 16);
      }
  };
  auto mmh = [&](int half) {
    __builtin_amdgcn_s_setprio(1);
#pragma unroll
    for (int mi = 0; mi < MH; ++mi)
#pragma unroll
      for (int ni = 0; ni < 2; ++ni)
#pragma unroll
        for (int kk = 0; kk < 2; ++kk)
          acc[mi][half * 2 + ni] =
              MFMA(af[mi][kk], bh[ni][kk], acc[mi][half * 2 + ni]);
    __builtin_amdgcn_s_setprio(0);
  };

  const int NT = K >> 6;
  for (int t = 0; t < NT; ++t) {
    __syncthreads();            // reads of tile t-1 done (all waves)
    stageA(t); stageB(t);
    __syncthreads();            // compiler drains vmcnt; tile t ready
    lda_all();
    ldb(0); mmh(0);
    ldb(1); mmh(1);
  }

  // ---- epilogue: C/D layout col = lane&15, row = (lane>>4)*4 + reg
  if constexpr (EPI == 1) {
#pragma unroll
    for (int ni = 0; ni < 4; ++ni) {
      int gn = n0 + wn * 64 + ni * 16 + l15;
      float bv = bias[gn];
#pragma unroll
      for (int mi = 0; mi < MH; ++mi)
#pragma unroll
        for (int rg = 0; rg < 4; ++rg) {
          int gm = m0 + mi * 16 + l4 * 4 + rg;
          Out[(size_t)gm * N + gn] = acc[mi][ni][rg] + bv;
        }
    }
  } else {
    const int sec = n0 >> 10;  // 1024-aligned: 0 Q, 1 K, 2 V
    if (sec < 2) {
      bfu* dst = (sec == 0) ? Qg : Kg;
      const float scale = (sec == 0) ? 0.18033688011112042f : 1.0f;  // log2e/8
#pragma unroll
      for (int ni = 0; ni < 4; ++ni) {
        int gn = n0 + wn * 64 + ni * 16 + l15;
        int rem = gn & 1023;
        int hh = rem >> 6, dk = rem & 63;
        float bv = bias[gn];
#pragma unroll
        for (int mi = 0; mi < MH; ++mi)
#pragma unroll
          for (int rg = 0; rg < 4; ++rg) {
            int gm = m0 + mi * 16 + l4 * 4 + rg;
            int bb = gm >> 11, ll = gm & 2047;
            dst[(((size_t)(bb * H_ + hh)) * L_ + ll) * DK_ + dk] =
                f2bf((acc[mi][ni][rg] + bv) * scale);
          }
      }
    } else {
      // V: sigma^-1-permuted transpose via LDS, BN/128 passes of 128 n-rows
      __syncthreads();
#pragma unroll
      for (int pass = 0; pass < BN / 128; ++pass) {
        if (wn * 64 >= pass * 128 && wn * 64 < pass * 128 + 128) {
#pragma unroll
          for (int ni = 0; ni < 4; ++ni) {
            int n_local = wn * 64 + ni * 16 + l15;
            int n_rel = n_local - pass * 128;
            int gn = n0 + n_local;
            float bv = bias[gn];
            int swzn = (n_rel & 7) << 4;
#pragma unroll
            for (int mi = 0; mi < MH; ++mi) {
              int m_base = mi * 16 + l4 * 4;
              int k6 = m_base & 63;
              int p0 = (m_base & ~63) |
                       ((k6 & 32) | (((k6 >> 2) & 3) << 3) | (((k6 >> 4) & 1) << 2));
              float v0 = acc[mi][ni][0] + bv, v1 = acc[mi][ni][1] + bv;
              float v2 = acc[mi][ni][2] + bv, v3 = acc[mi][ni][3] + bv;
              uint32_t w01, w23;
              asm("v_cvt_pk_bf16_f32 %0, %1, %2" : "=v"(w01) : "v"(v0), "v"(v1));
              asm("v_cvt_pk_bf16_f32 %0, %1, %2" : "=v"(w23) : "v"(v2), "v"(v3));
              *(uint32_t*)((char*)LDSb + n_rel * (BM * 2) + ((2 * p0) ^ swzn)) = w01;
              *(uint32_t*)((char*)LDSb + n_rel * (BM * 2) + ((2 * p0 + 4) ^ swzn)) = w23;
            }
          }
        }
        __syncthreads();
        {  // readers: TH threads over 128 n-rows x (BM/8) 16B chunks
          int n = tid / (TH / 128);
          int cb = (tid % (TH / 128)) * (BM / 8 / (TH / 128) * 1);
          // for TH=256: 2 thr/row, 8 chunks each; TH=128: 1 thr/row, 16 chunks
          int nch = (BM / 8) / (TH / 128);
          int gnn = n0 + pass * 128 + n;
          int hh = (gnn >> 6) & 15, dk = gnn & 63;
          size_t rowbase =
              (((size_t)((m0 >> 11) * H_ + hh)) * DK_ + dk) * L_ + (m0 & 2047);
#pragma unroll
          for (int j = 0; j < (BM / 8); ++j) {
            if (j >= nch) break;
            int ch = cb * nch / nch + (tid % (TH / 128)) * nch + j;
            ch = (tid % (TH / 128)) * nch + j;
            bf16x8 vv = *(const bf16x8*)((char*)LDSb + n * (BM * 2) +
                                         ((ch * 16) ^ ((n & 7) << 4)));
            *(bf16x8*)(Vtg + rowbase + ch * 8) = vv;
          }
        }
        __syncthreads();
      }
    }
  }
}

// ---------------- flash attention v3 (causal) ----------------
// 512 blocks; xcd = hid&7, 8 bh per XCD (K/V L2 locality). Block handles
// 128-row q-superblocks {p, 15-p} (34 KV tiles, perfect balance). 4 waves;
// wave owns 32 q rows (2 x 16). Q loaded directly to registers (no Q LDS).
// S^T = mfma(K,Q): lane owns softmax stats of one q-row per half. V stored
// sigma-permuted so packed P words ARE the PV A-fragment (no cross-lane).

__global__ __launch_bounds__(256, 3) void attn(const bfu* __restrict__ Qg,
                                               const bfu* __restrict__ Kg,
                                               const bfu* __restrict__ Vtg,
                                               bfu* __restrict__ Ao) {
  __shared__ __align__(16) bfu Ks[2 * 64 * 64];
  __shared__ __align__(16) bfu Vs[2 * 64 * 64];

  const int tid = threadIdx.x;
  const int lane = tid & 63;
  const int w = tid >> 6;
  const int l15 = lane & 15, l4 = lane >> 4;

  const int hid = blockIdx.x;            // 512 blocks
  const int xcd = hid & 7, slot = hid >> 3;
  const int bh = xcd * 8 + (slot >> 3);  // 8 bh per XCD
  const int p = slot & 7;
  const int b = bh >> 4, h = bh & 15;

  for (int seg = 0; seg < 2; ++seg) {
    const int qb = (seg == 0) ? p : 15 - p;   // 128-row superblock
    const int q0 = qb * 128;
    const int nt = 2 * qb + 2;
    const int q0w = q0 + w * 32;              // wave's first q row

    // ---- Q fragments straight from global (Qg pre-scaled by log2e/8)
    bf16x8 qf[2][2];
#pragma unroll
    for (int mi = 0; mi < 2; ++mi)
#pragma unroll
      for (int kk = 0; kk < 2; ++kk)
        qf[mi][kk] = *(const bf16x8*)(
            Qg + ((size_t)bh * L_ + q0w + mi * 16 + l15) * DK_ + kk * 32 + l4 * 8);

    // ---- stage KV tile 0 (buffer 0)
#pragma unroll
    for (int i = 0; i < 2; ++i) {
      int lb = i * 256 + tid;
      int r = lb >> 3, c16 = (lb & 7) ^ (r & 7);
      gll16(Kg + ((size_t)bh * L_ + r) * DK_ + c16 * 8, (char*)Ks + lb * 16);
      gll16(Vtg + ((size_t)bh * DK_ + r) * L_ + c16 * 8, (char*)Vs + lb * 16);
    }
    VMCNT(0);
    BARRIER();

    f32x4 acco[2][4] = {};          // [half][d-block]; row q = l4*4+rg
    float m[2] = {-1e30f, -1e30f};  // per-lane: q = l15 (per half)
    float l[2] = {0.f, 0.f};

    for (int t = 0; t < nt; ++t) {
      const int cur = t & 1;
      const int kv0 = t * 64;
      const char* Kc = (const char*)Ks + cur * 8192;
      const char* Vc = (const char*)Vs + cur * 8192;

      if (t + 1 < nt) {
        const int nb = (t + 1) & 1, nkv = (t + 1) * 64;
#pragma unroll
        for (int i = 0; i < 2; ++i) {
          int lb = i * 256 + tid;
          int r = lb >> 3, c16 = (lb & 7) ^ (r & 7);
          gll16(Kg + ((size_t)bh * L_ + nkv + r) * DK_ + c16 * 8,
                (char*)Ks + nb * 8192 + lb * 16);
          gll16(Vtg + ((size_t)bh * DK_ + r) * L_ + nkv + c16 * 8,
                (char*)Vs + nb * 8192 + lb * 16);
        }
        VMCNT(4);
      } else {
        VMCNT(0);
      }
      BARRIER();

      if (kv0 <= q0w + 31) {  // wave has unmasked rows in this tile
        // ---- S^T = K Q^T : s[mi][ni][rg] = S^T[kv=ni*16+l4*4+rg][q=l15]
        f32x4 s[2][4] = {};
        __builtin_amdgcn_s_setprio(1);
#pragma unroll
        for (int kk = 0; kk < 2; ++kk)
#pragma unroll
          for (int ni = 0; ni < 4; ++ni) {
            int r = ni * 16 + l15;
            int ch = (kk * 4 + l4) ^ (r & 7);
            bf16x8 kf = *(const bf16x8*)(Kc + r * 128 + ch * 16);
#pragma unroll
            for (int mi = 0; mi < 2; ++mi)
              s[mi][ni] = MFMA(kf, qf[mi][kk], s[mi][ni]);
          }
        __builtin_amdgcn_s_setprio(0);

        if (kv0 + 63 > q0w) {  // diagonal band: mask kv > q
#pragma unroll
          for (int mi = 0; mi < 2; ++mi) {
            int qg_ = q0w + mi * 16 + l15;
#pragma unroll
            for (int ni = 0; ni < 4; ++ni) {
              int kvg = kv0 + ni * 16 + l4 * 4;
#pragma unroll
              for (int rg = 0; rg < 4; ++rg)
                if (kvg + rg > qg_) s[mi][ni][rg] = -1e30f;
            }
          }
        }

        // ---- row max + defer-max rescale
        float mx[2];
#pragma unroll
        for (int mi = 0; mi < 2; ++mi) {
          float v = fmaxf(fmaxf(fmaxf(s[mi][0][0], s[mi][0][1]),
                                fmaxf(s[mi][0][2], s[mi][0][3])),
                          fmaxf(fmaxf(s[mi][1][0], s[mi][1][1]),
                                fmaxf(s[mi][1][2], s[mi][1][3])));
          v = fmaxf(v, fmaxf(fmaxf(fmaxf(s[mi][2][0], s[mi][2][1]),
                                   fmaxf(s[mi][2][2], s[mi][2][3])),
                             fmaxf(fmaxf(s[mi][3][0], s[mi][3][1]),
                                   fmaxf(s[mi][3][2], s[mi][3][3]))));
          v = fmaxf(v, __shfl_xor(v, 16));
          v = fmaxf(v, __shfl_xor(v, 32));
          mx[mi] = v;
        }
        float grow = fmaxf(mx[0] - m[0], mx[1] - m[1]);
        if (__any(grow > 11.0f)) {
#pragma unroll
          for (int mi = 0; mi < 2; ++mi) {
            float mn = fmaxf(m[mi], mx[mi]);
            float sc = __builtin_amdgcn_exp2f(m[mi] - mn);
            m[mi] = mn;
            l[mi] *= sc;
#pragma unroll
            for (int rg = 0; rg < 4; ++rg) {
              float scq = __shfl(sc, l4 * 4 + rg);
              acco[mi][0][rg] *= scq; acco[mi][1][rg] *= scq;
              acco[mi][2][rg] *= scq; acco[mi][3][rg] *= scq;
            }
          }
        }

        // ---- P = exp2(S^T - m), pack bf16 pairs (kv ascending)
        uint32_t pk[2][4][2];
#pragma unroll
        for (int mi = 0; mi < 2; ++mi)
#pragma unroll
          for (int ni = 0; ni < 4; ++ni) {
            float p0 = __builtin_amdgcn_exp2f(s[mi][ni][0] - m[mi]);
            float p1 = __builtin_amdgcn_exp2f(s[mi][ni][1] - m[mi]);
            float p2 = __builtin_amdgcn_exp2f(s[mi][ni][2] - m[mi]);
            float p3 = __builtin_amdgcn_exp2f(s[mi][ni][3] - m[mi]);
            l[mi] += (p0 + p1) + (p2 + p3);
            asm("v_cvt_pk_bf16_f32 %0, %1, %2" : "=v"(pk[mi][ni][0]) : "v"(p0), "v"(p1));
            asm("v_cvt_pk_bf16_f32 %0, %1, %2" : "=v"(pk[mi][ni][1]) : "v"(p2), "v"(p3));
          }

        // ---- O += P V : pk words ARE the A-frag (V kv-cols pre-permuted)
        __builtin_amdgcn_s_setprio(1);
#pragma unroll
        for (int kk = 0; kk < 2; ++kk) {
          union { uint32_t wd[4]; bf16x8 v; } u[2];
#pragma unroll
          for (int mi = 0; mi < 2; ++mi) {
            u[mi].wd[0] = pk[mi][2 * kk][0];
            u[mi].wd[1] = pk[mi][2 * kk][1];
            u[mi].wd[2] = pk[mi][2 * kk + 1][0];
            u[mi].wd[3] = pk[mi][2 * kk + 1][1];
          }
#pragma unroll
          for (int ni = 0; ni < 4; ++ni) {
            int r = ni * 16 + l15;
            int ch = (kk * 4 + l4) ^ (r & 7);
            bf16x8 vf = *(const bf16x8*)(Vc + r * 128 + ch * 16);
#pragma unroll
            for (int mi = 0; mi < 2; ++mi)
              acco[mi][ni] = MFMA(u[mi].v, vf, acco[mi][ni]);
          }
        }
        __builtin_amdgcn_s_setprio(0);
      }  // active wave

      BARRIER();  // all waves done with buf[cur]
    }

    // ---- epilogue
#pragma unroll
    for (int mi = 0; mi < 2; ++mi) {
      float ls = l[mi];
      ls += __shfl_xor(ls, 16);
      ls += __shfl_xor(ls, 32);
      float linv = 1.0f / ls;
#pragma unroll
      for (int rg = 0; rg < 4; ++rg) {
        float lq = __shfl(linv, l4 * 4 + rg);
        int q = q0w + mi * 16 + l4 * 4 + rg;
#pragma unroll
        for (int ni = 0; ni < 4; ++ni) {
          int d = ni * 16 + l15;
          Ao[((size_t)b * L_ + q) * D_ + h * DK_ + d] = f2bf(acco[mi][ni][rg] * lq);
        }
      }
    }
  }  // seg
}

// ---------------- launch ----------------

extern "C" void kernel_launch(void* const* d_in, const int* in_sizes, int n_in,
                              void* d_out, int out_size, void* d_ws, size_t ws_size,
                              hipStream_t stream) {
  const float* x = (const float*)d_in[0];
  const float* W_qkv = (const float*)d_in[1];
  const float* b_qkv = (const float*)d_in[2];
  const float* W_out = (const float*)d_in[3];
  const float* b_out = (const float*)d_in[4];
  float* out = (float*)d_out;

  char* ws = (char*)d_ws;
  bfu* xb     = (bfu*)(ws);                    // 8192*1024*2   = 16,777,216
  bfu* Wqkv_t = (bfu*)(ws + 16777216);         // 3072*1024*2   =  6,291,456
  bfu* Wout_t = (bfu*)(ws + 23068672);         // 1024*1024*2   =  2,097,152
  bfu* Qg     = (bfu*)(ws + 25165824);         // 16,777,216
  bfu* Kg     = (bfu*)(ws + 41943040);         // 16,777,216
  bfu* Vtg    = (bfu*)(ws + 58720256);         // 16,777,216
  bfu* Ao     = (bfu*)(ws + 75497472);         // 16,777,216  (total ~92.3 MB)

  cast_x<<<8192, 256, 0, stream>>>(x, xb, 2097152);
  transpose_cast<<<dim3(96, 32), dim3(32, 8), 0, stream>>>(W_qkv, Wqkv_t, 1024, 3072);
  transpose_cast<<<dim3(32, 32), dim3(32, 8), 0, stream>>>(W_out, Wout_t, 1024, 1024);

  // gemm0: 128x256 tiles, 4 waves (per-wave 128x64), grid 64m x 12n = 768
  gemm_w<0, 128, 256, 4><<<768, 256, 0, stream>>>(
      xb, Wqkv_t, b_qkv, Qg, Kg, Vtg, nullptr, 8192, 3072, 1024);
  attn<<<512, 256, 0, stream>>>(Qg, Kg, Vtg, Ao);
  // gemm1: 128x128 tiles, 2 waves (per-wave 128x64), grid 64m x 8n = 512
  gemm_w<1, 128, 128, 2><<<512, 128, 0, stream>>>(
      Ao, Wout_t, b_out, nullptr, nullptr, nullptr, out, 8192, 1024, 1024);
}

// Round 11
// 163.874 us; speedup vs baseline: 1.1094x; 1.0679x over previous
//
#include <hip/hip_runtime.h>
#include <stdint.h>

#define B_ 4
#define L_ 2048
#define D_ 1024
#define H_ 16
#define DK_ 64

typedef __attribute__((ext_vector_type(8))) short bf16x8;
typedef __attribute__((ext_vector_type(4))) float f32x4;
typedef unsigned short bfu;   // raw bf16 storage

#define MFMA(a, b, c) __builtin_amdgcn_mfma_f32_16x16x32_bf16((a), (b), (c), 0, 0, 0)

__device__ __forceinline__ unsigned short f2bf(float f) {
  union { float f; unsigned int u; } v; v.f = f;
  unsigned int u = v.u;
  return (unsigned short)((u + 0x7fffu + ((u >> 16) & 1u)) >> 16);  // RNE
}

__device__ __forceinline__ void gll16(const void* g, void* l) {
  __builtin_amdgcn_global_load_lds(
      (const __attribute__((address_space(1))) void*)g,
      (__attribute__((address_space(3))) void*)l, 16, 0, 0);
}

#define VMCNT(n_) asm volatile("s_waitcnt vmcnt(" #n_ ")" ::: "memory")
#define BARRIER() asm volatile("s_barrier" ::: "memory")

// ---------------- prep kernels ----------------

__global__ __launch_bounds__(256) void cast_x(const float* __restrict__ in,
                                              bfu* __restrict__ out, int n4) {
  int i = blockIdx.x * 256 + threadIdx.x;
  if (i >= n4) return;
  float4 v = ((const float4*)in)[i];
  ushort4 o;
  o.x = f2bf(v.x); o.y = f2bf(v.y); o.z = f2bf(v.z); o.w = f2bf(v.w);
  ((ushort4*)out)[i] = o;
}

// W[K][C] fp32 -> B-fragment-packed bf16: block (c>>4, k>>3) of 128 bfu,
// within block: (c&15)*8 + (k&7). A wave's B-frag load is then one fully
// coalesced 256B run per 16 lanes.
__global__ __launch_bounds__(256) void wpack(const float* __restrict__ in,
                                             bfu* __restrict__ out, int K, int C) {
  int idx = blockIdx.x * 256 + threadIdx.x;
  if (idx >= K * C) return;
  int k = idx / C, c = idx % C;
  size_t o = ((size_t)(c >> 4) * (K >> 3) + (k >> 3)) * 128 + (c & 15) * 8 + (k & 7);
  out[o] = f2bf(in[idx]);
}

// ---------------- reg-B GEMM: A in LDS (dbuf), B global->reg direct --------
// C[M][N] = A[M][K] * B[K][N] with B frag-packed (Bp). 256 thr = 4 waves
// (2m x 2n), per-wave 64x64 (acc[4][4]). BK=64. Per K-tile: ONE vmcnt(8) +
// ONE barrier; A staged 1 tile ahead via gll16 (4/thread), B loaded 2 tiles
// ahead into named reg buffers brA/brB (8 coalesced 16B loads/lane).
// Queue at body(t): [B(t):8, A(t):4, B(t+1):8] -> vmcnt(8) retires A(t),B(t)
// with >=1-tile slack. sched_barrier(0) pins stageA-before-loadB issue order.
// Supertile swizzle: XCD owns 8-m-tile band (A L2-resident), sweeps n.
// EPI 0: scatter Q (scaled log2e/8), K, V (sigma^-1-permuted transpose via
// LDS). EPI 1: fp32 out += bias.

template <int EPI>
__global__ __launch_bounds__(256, 2) void gemm_r(
    const bfu* __restrict__ A, const bfu* __restrict__ Bp,
    const float* __restrict__ bias, bfu* __restrict__ Qg, bfu* __restrict__ Kg,
    bfu* __restrict__ Vtg, float* __restrict__ Out, int M, int N, int K) {
  __shared__ __align__(16) bfu As[2][128 * 64];  // 32 KB total
  const int tid = threadIdx.x;
  const int lane = tid & 63;
  const int w = tid >> 6;
  const int wm = w >> 1, wn = w & 1;
  const int l15 = lane & 15, l4 = lane >> 4;

  const int nwg = gridDim.x;
  const int cpx = nwg >> 3;
  const int bid = (int)blockIdx.x;
  const int swz = (bid & 7) * cpx + (bid >> 3);
  const int NTt = N / 128;
  const int m0 = ((swz & 7) + 8 * (swz / (8 * NTt))) * 128;
  const int n0 = ((swz >> 3) % NTt) * 128;
  const int K8 = K >> 3;

  auto stageA = [&](int t) {
    char* lb = (char*)As[t & 1];
#pragma unroll
    for (int j = 0; j < 4; ++j) {
      int idx = j * 256 + tid;
      int row = idx >> 3, c16p = idx & 7, c16 = c16p ^ (row & 7);
      gll16(A + (size_t)(m0 + row) * K + t * 64 + c16 * 8,
            lb + row * 128 + c16p * 16);
    }
  };

  const size_t bbase = ((size_t)((n0 + wn * 64) >> 4)) * K8;
  auto loadB = [&](int t, bf16x8 (&br)[4][2]) {
#pragma unroll
    for (int ni = 0; ni < 4; ++ni)
#pragma unroll
      for (int kk = 0; kk < 2; ++kk)
        br[ni][kk] = *(const bf16x8*)(
            Bp + (bbase + (size_t)ni * K8 + t * 8 + kk * 4 + l4) * 128 + l15 * 8);
  };

  f32x4 acc[4][4] = {};
  bf16x8 af[4][2], brA[4][2], brB[4][2];

  auto lda = [&](int t) {
    const char* base = (const char*)As[t & 1];
#pragma unroll
    for (int mi = 0; mi < 4; ++mi)
#pragma unroll
      for (int kk = 0; kk < 2; ++kk) {
        int row = wm * 64 + mi * 16 + l15;
        int ch = (kk * 4 + l4) ^ (row & 7);
        af[mi][kk] = *(const bf16x8*)(base + row * 128 + ch * 16);
      }
  };
  auto mm_all = [&](bf16x8 (&br)[4][2]) {
    __builtin_amdgcn_s_setprio(1);
#pragma unroll
    for (int kk = 0; kk < 2; ++kk)
#pragma unroll
      for (int mi = 0; mi < 4; ++mi)
#pragma unroll
        for (int ni = 0; ni < 4; ++ni)
          acc[mi][ni] = MFMA(af[mi][kk], br[ni][kk], acc[mi][ni]);
    __builtin_amdgcn_s_setprio(0);
  };

  const int NT = K >> 6;  // 16, even
  // prologue: A(0) first (oldest), then B(0), B(1)
  stageA(0);
  __builtin_amdgcn_sched_barrier(0);
  loadB(0, brA);
  loadB(1, brB);

  for (int t = 0; t < NT; t += 2) {
    // even tile t: consume brA
    VMCNT(8); BARRIER();             // retires A(t), B(t)
    lda(t);
    stageA(t + 1);                   // t+1 < NT always (NT even)
    __builtin_amdgcn_sched_barrier(0);
    mm_all(brA);
    if (t + 2 < NT) loadB(t + 2, brA);
    // odd tile t+1: consume brB
    if (t + 2 < NT) { VMCNT(8); } else { VMCNT(0); }
    BARRIER();                       // retires A(t+1), B(t+1)
    lda(t + 1);
    if (t + 2 < NT) stageA(t + 2);
    __builtin_amdgcn_sched_barrier(0);
    mm_all(brB);
    if (t + 3 < NT) loadB(t + 3, brB);
  }

  // ---- epilogue: C/D layout col = lane&15, row = (lane>>4)*4 + reg
  if constexpr (EPI == 1) {
#pragma unroll
    for (int ni = 0; ni < 4; ++ni) {
      int gn = n0 + wn * 64 + ni * 16 + l15;
      float bv = bias[gn];
#pragma unroll
      for (int mi = 0; mi < 4; ++mi)
#pragma unroll
        for (int rg = 0; rg < 4; ++rg) {
          int gm = m0 + wm * 64 + mi * 16 + l4 * 4 + rg;
          Out[(size_t)gm * N + gn] = acc[mi][ni][rg] + bv;
        }
    }
  } else {
    const int sec = n0 >> 10;  // 0 Q, 1 K, 2 V (1024-wide sections)
    if (sec < 2) {
      bfu* dst = (sec == 0) ? Qg : Kg;
      const float scale = (sec == 0) ? 0.18033688011112042f : 1.0f;  // log2e/8
#pragma unroll
      for (int ni = 0; ni < 4; ++ni) {
        int gn = n0 + wn * 64 + ni * 16 + l15;
        int rem = gn & 1023;
        int hh = rem >> 6, dk = rem & 63;
        float bv = bias[gn];
#pragma unroll
        for (int mi = 0; mi < 4; ++mi)
#pragma unroll
          for (int rg = 0; rg < 4; ++rg) {
            int gm = m0 + wm * 64 + mi * 16 + l4 * 4 + rg;
            int bb = gm >> 11, ll = gm & 2047;
            dst[(((size_t)(bb * H_ + hh)) * L_ + ll) * DK_ + dk] =
                f2bf((acc[mi][ni][rg] + bv) * scale);
          }
      }
    } else {
      // V: sigma^-1-permuted transpose via LDS (128n x 128m x 2B = 32 KB)
      __syncthreads();  // K-loop LDS use + outstanding gll16 drained
#pragma unroll
      for (int ni = 0; ni < 4; ++ni) {
        int n_local = wn * 64 + ni * 16 + l15;
        int gn = n0 + n_local;
        float bv = bias[gn];
        int swzn = (n_local & 7) << 4;
#pragma unroll
        for (int mi = 0; mi < 4; ++mi) {
          int m_base = wm * 64 + mi * 16 + l4 * 4;
          int k6 = m_base & 63;
          int p0 = (m_base & ~63) |
                   ((k6 & 32) | (((k6 >> 2) & 3) << 3) | (((k6 >> 4) & 1) << 2));
          float v0 = acc[mi][ni][0] + bv, v1 = acc[mi][ni][1] + bv;
          float v2 = acc[mi][ni][2] + bv, v3 = acc[mi][ni][3] + bv;
          uint32_t w01, w23;
          asm("v_cvt_pk_bf16_f32 %0, %1, %2" : "=v"(w01) : "v"(v0), "v"(v1));
          asm("v_cvt_pk_bf16_f32 %0, %1, %2" : "=v"(w23) : "v"(v2), "v"(v3));
          *(uint32_t*)((char*)As + n_local * 256 + ((2 * p0) ^ swzn)) = w01;
          *(uint32_t*)((char*)As + n_local * 256 + ((2 * p0 + 4) ^ swzn)) = w23;
        }
      }
      __syncthreads();
      int n = tid >> 1;            // 2 threads per n-row
      int cb = (tid & 1) * 8;      // 8 x 16B chunks each (16 total = 128 m)
      int gnn = n0 + n;
      int hh = (gnn >> 6) & 15, dk = gnn & 63;
      size_t rowbase =
          (((size_t)((m0 >> 11) * H_ + hh)) * DK_ + dk) * L_ + (m0 & 2047);
#pragma unroll
      for (int j = 0; j < 8; ++j) {
        int ch = cb + j;
        bf16x8 vv = *(const bf16x8*)((char*)As + n * 256 +
                                     ((ch * 16) ^ ((n & 7) << 4)));
        *(bf16x8*)(Vtg + rowbase + ch * 8) = vv;
      }
    }
  }
}

// ---------------- flash attention v3 (causal) ----------------
// 512 blocks; xcd = hid&7, 8 bh per XCD (K/V L2 locality). Block handles
// 128-row q-superblocks {p, 15-p} (34 KV tiles, perfect balance). 4 waves;
// wave owns 32 q rows (2 x 16). Q loaded directly to registers (no Q LDS).
// S^T = mfma(K,Q): lane owns softmax stats of one q-row per half. V stored
// sigma-permuted so packed P words ARE the PV A-fragment (no cross-lane).

__global__ __launch_bounds__(256, 3) void attn(const bfu* __restrict__ Qg,
                                               const bfu* __restrict__ Kg,
                                               const bfu* __restrict__ Vtg,
                                               bfu* __restrict__ Ao) {
  __shared__ __align__(16) bfu Ks[2 * 64 * 64];
  __shared__ __align__(16) bfu Vs[2 * 64 * 64];

  const int tid = threadIdx.x;
  const int lane = tid & 63;
  const int w = tid >> 6;
  const int l15 = lane & 15, l4 = lane >> 4;

  const int hid = blockIdx.x;            // 512 blocks
  const int xcd = hid & 7, slot = hid >> 3;
  const int bh = xcd * 8 + (slot >> 3);  // 8 bh per XCD
  const int p = slot & 7;
  const int b = bh >> 4, h = bh & 15;

  for (int seg = 0; seg < 2; ++seg) {
    const int qb = (seg == 0) ? p : 15 - p;   // 128-row superblock
    const int q0 = qb * 128;
    const int nt = 2 * qb + 2;
    const int q0w = q0 + w * 32;              // wave's first q row

    // ---- Q fragments straight from global (Qg pre-scaled by log2e/8)
    bf16x8 qf[2][2];
#pragma unroll
    for (int mi = 0; mi < 2; ++mi)
#pragma unroll
      for (int kk = 0; kk < 2; ++kk)
        qf[mi][kk] = *(const bf16x8*)(
            Qg + ((size_t)bh * L_ + q0w + mi * 16 + l15) * DK_ + kk * 32 + l4 * 8);

    // ---- stage KV tile 0 (buffer 0)
#pragma unroll
    for (int i = 0; i < 2; ++i) {
      int lb = i * 256 + tid;
      int r = lb >> 3, c16 = (lb & 7) ^ (r & 7);
      gll16(Kg + ((size_t)bh * L_ + r) * DK_ + c16 * 8, (char*)Ks + lb * 16);
      gll16(Vtg + ((size_t)bh * DK_ + r) * L_ + c16 * 8, (char*)Vs + lb * 16);
    }
    VMCNT(0);
    BARRIER();

    f32x4 acco[2][4] = {};          // [half][d-block]; row q = l4*4+rg
    float m[2] = {-1e30f, -1e30f};  // per-lane: q = l15 (per half)
    float l[2] = {0.f, 0.f};

    for (int t = 0; t < nt; ++t) {
      const int cur = t & 1;
      const int kv0 = t * 64;
      const char* Kc = (const char*)Ks + cur * 8192;
      const char* Vc = (const char*)Vs + cur * 8192;

      if (t + 1 < nt) {
        const int nb = (t + 1) & 1, nkv = (t + 1) * 64;
#pragma unroll
        for (int i = 0; i < 2; ++i) {
          int lb = i * 256 + tid;
          int r = lb >> 3, c16 = (lb & 7) ^ (r & 7);
          gll16(Kg + ((size_t)bh * L_ + nkv + r) * DK_ + c16 * 8,
                (char*)Ks + nb * 8192 + lb * 16);
          gll16(Vtg + ((size_t)bh * DK_ + r) * L_ + nkv + c16 * 8,
                (char*)Vs + nb * 8192 + lb * 16);
        }
        VMCNT(4);
      } else {
        VMCNT(0);
      }
      BARRIER();

      if (kv0 <= q0w + 31) {  // wave has unmasked rows in this tile
        // ---- S^T = K Q^T : s[mi][ni][rg] = S^T[kv=ni*16+l4*4+rg][q=l15]
        f32x4 s[2][4] = {};
        __builtin_amdgcn_s_setprio(1);
#pragma unroll
        for (int kk = 0; kk < 2; ++kk)
#pragma unroll
          for (int ni = 0; ni < 4; ++ni) {
            int r = ni * 16 + l15;
            int ch = (kk * 4 + l4) ^ (r & 7);
            bf16x8 kf = *(const bf16x8*)(Kc + r * 128 + ch * 16);
#pragma unroll
            for (int mi = 0; mi < 2; ++mi)
              s[mi][ni] = MFMA(kf, qf[mi][kk], s[mi][ni]);
          }
        __builtin_amdgcn_s_setprio(0);

        if (kv0 + 63 > q0w) {  // diagonal band: mask kv > q
#pragma unroll
          for (int mi = 0; mi < 2; ++mi) {
            int qg_ = q0w + mi * 16 + l15;
#pragma unroll
            for (int ni = 0; ni < 4; ++ni) {
              int kvg = kv0 + ni * 16 + l4 * 4;
#pragma unroll
              for (int rg = 0; rg < 4; ++rg)
                if (kvg + rg > qg_) s[mi][ni][rg] = -1e30f;
            }
          }
        }

        // ---- row max + defer-max rescale
        float mx[2];
#pragma unroll
        for (int mi = 0; mi < 2; ++mi) {
          float v = fmaxf(fmaxf(fmaxf(s[mi][0][0], s[mi][0][1]),
                                fmaxf(s[mi][0][2], s[mi][0][3])),
                          fmaxf(fmaxf(s[mi][1][0], s[mi][1][1]),
                                fmaxf(s[mi][1][2], s[mi][1][3])));
          v = fmaxf(v, fmaxf(fmaxf(fmaxf(s[mi][2][0], s[mi][2][1]),
                                   fmaxf(s[mi][2][2], s[mi][2][3])),
                             fmaxf(fmaxf(s[mi][3][0], s[mi][3][1]),
                                   fmaxf(s[mi][3][2], s[mi][3][3]))));
          v = fmaxf(v, __shfl_xor(v, 16));
          v = fmaxf(v, __shfl_xor(v, 32));
          mx[mi] = v;
        }
        float grow = fmaxf(mx[0] - m[0], mx[1] - m[1]);
        if (__any(grow > 11.0f)) {
#pragma unroll
          for (int mi = 0; mi < 2; ++mi) {
            float mn = fmaxf(m[mi], mx[mi]);
            float sc = __builtin_amdgcn_exp2f(m[mi] - mn);
            m[mi] = mn;
            l[mi] *= sc;
#pragma unroll
            for (int rg = 0; rg < 4; ++rg) {
              float scq = __shfl(sc, l4 * 4 + rg);
              acco[mi][0][rg] *= scq; acco[mi][1][rg] *= scq;
              acco[mi][2][rg] *= scq; acco[mi][3][rg] *= scq;
            }
          }
        }

        // ---- P = exp2(S^T - m), pack bf16 pairs (kv ascending)
        uint32_t pk[2][4][2];
#pragma unroll
        for (int mi = 0; mi < 2; ++mi)
#pragma unroll
          for (int ni = 0; ni < 4; ++ni) {
            float p0 = __builtin_amdgcn_exp2f(s[mi][ni][0] - m[mi]);
            float p1 = __builtin_amdgcn_exp2f(s[mi][ni][1] - m[mi]);
            float p2 = __builtin_amdgcn_exp2f(s[mi][ni][2] - m[mi]);
            float p3 = __builtin_amdgcn_exp2f(s[mi][ni][3] - m[mi]);
            l[mi] += (p0 + p1) + (p2 + p3);
            asm("v_cvt_pk_bf16_f32 %0, %1, %2" : "=v"(pk[mi][ni][0]) : "v"(p0), "v"(p1));
            asm("v_cvt_pk_bf16_f32 %0, %1, %2" : "=v"(pk[mi][ni][1]) : "v"(p2), "v"(p3));
          }

        // ---- O += P V : pk words ARE the A-frag (V kv-cols pre-permuted)
        __builtin_amdgcn_s_setprio(1);
#pragma unroll
        for (int kk = 0; kk < 2; ++kk) {
          union { uint32_t wd[4]; bf16x8 v; } u[2];
#pragma unroll
          for (int mi = 0; mi < 2; ++mi) {
            u[mi].wd[0] = pk[mi][2 * kk][0];
            u[mi].wd[1] = pk[mi][2 * kk][1];
            u[mi].wd[2] = pk[mi][2 * kk + 1][0];
            u[mi].wd[3] = pk[mi][2 * kk + 1][1];
          }
#pragma unroll
          for (int ni = 0; ni < 4; ++ni) {
            int r = ni * 16 + l15;
            int ch = (kk * 4 + l4) ^ (r & 7);
            bf16x8 vf = *(const bf16x8*)(Vc + r * 128 + ch * 16);
#pragma unroll
            for (int mi = 0; mi < 2; ++mi)
              acco[mi][ni] = MFMA(u[mi].v, vf, acco[mi][ni]);
          }
        }
        __builtin_amdgcn_s_setprio(0);
      }  // active wave

      BARRIER();  // all waves done with buf[cur]
    }

    // ---- epilogue
#pragma unroll
    for (int mi = 0; mi < 2; ++mi) {
      float ls = l[mi];
      ls += __shfl_xor(ls, 16);
      ls += __shfl_xor(ls, 32);
      float linv = 1.0f / ls;
#pragma unroll
      for (int rg = 0; rg < 4; ++rg) {
        float lq = __shfl(linv, l4 * 4 + rg);
        int q = q0w + mi * 16 + l4 * 4 + rg;
#pragma unroll
        for (int ni = 0; ni < 4; ++ni) {
          int d = ni * 16 + l15;
          Ao[((size_t)b * L_ + q) * D_ + h * DK_ + d] = f2bf(acco[mi][ni][rg] * lq);
        }
      }
    }
  }  // seg
}

// ---------------- launch ----------------

extern "C" void kernel_launch(void* const* d_in, const int* in_sizes, int n_in,
                              void* d_out, int out_size, void* d_ws, size_t ws_size,
                              hipStream_t stream) {
  const float* x = (const float*)d_in[0];
  const float* W_qkv = (const float*)d_in[1];
  const float* b_qkv = (const float*)d_in[2];
  const float* W_out = (const float*)d_in[3];
  const float* b_out = (const float*)d_in[4];
  float* out = (float*)d_out;

  char* ws = (char*)d_ws;
  bfu* xb     = (bfu*)(ws);                    // 8192*1024*2   = 16,777,216
  bfu* Wqkv_p = (bfu*)(ws + 16777216);         // 3072*1024*2   =  6,291,456
  bfu* Wout_p = (bfu*)(ws + 23068672);         // 1024*1024*2   =  2,097,152
  bfu* Qg     = (bfu*)(ws + 25165824);         // 16,777,216
  bfu* Kg     = (bfu*)(ws + 41943040);         // 16,777,216
  bfu* Vtg    = (bfu*)(ws + 58720256);         // 16,777,216
  bfu* Ao     = (bfu*)(ws + 75497472);         // 16,777,216  (total ~92.3 MB)

  cast_x<<<8192, 256, 0, stream>>>(x, xb, 2097152);
  wpack<<<12288, 256, 0, stream>>>(W_qkv, Wqkv_p, 1024, 3072);
  wpack<<<4096, 256, 0, stream>>>(W_out, Wout_p, 1024, 1024);

  // gemm0: 128x128 tiles, grid 64m x 24n = 1536, 2 blocks/CU
  gemm_r<0><<<1536, 256, 0, stream>>>(xb, Wqkv_p, b_qkv, Qg, Kg, Vtg, nullptr,
                                      8192, 3072, 1024);
  attn<<<512, 256, 0, stream>>>(Qg, Kg, Vtg, Ao);
  // gemm1: 128x128 tiles, grid 64m x 8n = 512
  gemm_r<1><<<512, 256, 0, stream>>>(Ao, Wout_p, b_out, nullptr, nullptr, nullptr,
                                     out, 8192, 1024, 1024);
}

// Round 12
// 160.952 us; speedup vs baseline: 1.1296x; 1.0182x over previous
//
#include <hip/hip_runtime.h>
#include <stdint.h>

#define B_ 4
#define L_ 2048
#define D_ 1024
#define H_ 16
#define DK_ 64

typedef __attribute__((ext_vector_type(8))) short bf16x8;
typedef __attribute__((ext_vector_type(4))) float f32x4;
typedef unsigned short bfu;   // raw bf16 storage

#define MFMA(a, b, c) __builtin_amdgcn_mfma_f32_16x16x32_bf16((a), (b), (c), 0, 0, 0)

__device__ __forceinline__ unsigned short f2bf(float f) {
  union { float f; unsigned int u; } v; v.f = f;
  unsigned int u = v.u;
  return (unsigned short)((u + 0x7fffu + ((u >> 16) & 1u)) >> 16);  // RNE
}

__device__ __forceinline__ void gll16(const void* g, void* l) {
  __builtin_amdgcn_global_load_lds(
      (const __attribute__((address_space(1))) void*)g,
      (__attribute__((address_space(3))) void*)l, 16, 0, 0);
}

#define VMCNT(n_) asm volatile("s_waitcnt vmcnt(" #n_ ")" ::: "memory")
#define BARRIER() asm volatile("s_barrier" ::: "memory")

// ---------------- prep kernels ----------------

__global__ __launch_bounds__(256) void cast_x(const float* __restrict__ in,
                                              bfu* __restrict__ out, int n4) {
  int i = blockIdx.x * 256 + threadIdx.x;
  if (i >= n4) return;
  float4 v = ((const float4*)in)[i];
  ushort4 o;
  o.x = f2bf(v.x); o.y = f2bf(v.y); o.z = f2bf(v.z); o.w = f2bf(v.w);
  ((ushort4*)out)[i] = o;
}

// W[K][C] fp32 -> B-fragment-packed bf16: block (c>>4, k>>3) of 128 bfu,
// within block (c&15)*8 + (k&7). Vectorized: thread owns (kb, c), 8 coalesced
// row-reads, one 16B write.
__global__ __launch_bounds__(256) void wpack2(const float* __restrict__ in,
                                              bfu* __restrict__ out, int K, int C) {
  int idx = blockIdx.x * 256 + threadIdx.x;
  int c = idx % C, kb = idx / C;
  if (kb >= (K >> 3)) return;
  unsigned short v[8];
#pragma unroll
  for (int j = 0; j < 8; ++j) v[j] = f2bf(in[(size_t)(kb * 8 + j) * C + c]);
  size_t o = ((size_t)(c >> 4) * (K >> 3) + kb) * 128 + (c & 15) * 8;
  *(ushort4*)(out + o) = make_ushort4(v[0], v[1], v[2], v[3]);
  *(ushort4*)(out + o + 4) = make_ushort4(v[4], v[5], v[6], v[7]);
}

// ------- gemm0: A in LDS (dbuf), B global->reg, per-wave 64x128 ------------
// C[M][N] = A[M][K]*B[K][N], B frag-packed. 256 thr = 4 waves (2m x 2n),
// tile 128x256, per-wave 64x128: acc[4][8]. LDS ceiling nu/158 -> 81%;
// L2 cap F(1/64+1/256) -> 70%. B consumed in two 4-colblock halves (brX/brY),
// prefetched ~half-tile ahead; ONE vmcnt(0)+barrier per K-tile.
// EPI: scatter Q (scaled log2e/8), K, V (sigma^-1-permuted transpose via LDS,
// 2 passes of 128 cols).

__global__ __launch_bounds__(256, 2) void gemm_n(
    const bfu* __restrict__ A, const bfu* __restrict__ Bp,
    const float* __restrict__ bias, bfu* __restrict__ Qg, bfu* __restrict__ Kg,
    bfu* __restrict__ Vtg, int M, int N, int K) {
  __shared__ __align__(16) bfu As[2][128 * 64];  // 32 KB
  const int tid = threadIdx.x;
  const int lane = tid & 63;
  const int w = tid >> 6;
  const int wm = w >> 1, wn = w & 1;
  const int l15 = lane & 15, l4 = lane >> 4;

  const int nwg = gridDim.x;
  const int cpx = nwg >> 3;
  const int bid = (int)blockIdx.x;
  const int swz = (bid & 7) * cpx + (bid >> 3);
  const int NTt = N / 256;
  const int m0 = ((swz & 7) + 8 * (swz / (8 * NTt))) * 128;
  const int n0 = ((swz >> 3) % NTt) * 256;
  const int K8 = K >> 3;

  auto stageA = [&](int t) {
    char* lb = (char*)As[t & 1];
#pragma unroll
    for (int j = 0; j < 4; ++j) {
      int idx = j * 256 + tid;
      int row = idx >> 3, c16p = idx & 7, c16 = c16p ^ (row & 7);
      gll16(A + (size_t)(m0 + row) * K + t * 64 + c16 * 8,
            lb + row * 128 + c16p * 16);
    }
  };

  const size_t bbase = ((size_t)((n0 + wn * 128) >> 4)) * K8;
  auto loadB = [&](int t, int h, bf16x8 (&br)[4][2]) {
#pragma unroll
    for (int ni = 0; ni < 4; ++ni)
#pragma unroll
      for (int kk = 0; kk < 2; ++kk)
        br[ni][kk] = *(const bf16x8*)(
            Bp + (bbase + (size_t)(h * 4 + ni) * K8 + t * 8 + kk * 4 + l4) * 128 +
            l15 * 8);
  };

  f32x4 acc[4][8] = {};
  bf16x8 af[4][2], brX[4][2], brY[4][2];

  auto lda = [&](int t) {
    const char* base = (const char*)As[t & 1];
#pragma unroll
    for (int mi = 0; mi < 4; ++mi)
#pragma unroll
      for (int kk = 0; kk < 2; ++kk) {
        int row = wm * 64 + mi * 16 + l15;
        int ch = (kk * 4 + l4) ^ (row & 7);
        af[mi][kk] = *(const bf16x8*)(base + row * 128 + ch * 16);
      }
  };
  auto mm_half = [&](bf16x8 (&br)[4][2], int h) {
    __builtin_amdgcn_s_setprio(1);
#pragma unroll
    for (int kk = 0; kk < 2; ++kk)
#pragma unroll
      for (int mi = 0; mi < 4; ++mi)
#pragma unroll
        for (int ni = 0; ni < 4; ++ni)
          acc[mi][h * 4 + ni] = MFMA(af[mi][kk], br[ni][kk], acc[mi][h * 4 + ni]);
    __builtin_amdgcn_s_setprio(0);
  };

  const int NT = K >> 6;
  stageA(0);
  __builtin_amdgcn_sched_barrier(0);
  loadB(0, 0, brX);

  for (int t = 0; t < NT; ++t) {
    VMCNT(0); BARRIER();                 // A(t) staged (all waves), brX landed
    lda(t);
    loadB(t, 1, brY);
    if (t + 1 < NT) stageA(t + 1);
    __builtin_amdgcn_sched_barrier(0);
    mm_half(brX, 0);
    if (t + 1 < NT) loadB(t + 1, 0, brX);
    mm_half(brY, 1);                     // compiler auto-waits brY
  }

  // ---- epilogue: C/D layout col = lane&15, row = (lane>>4)*4 + reg
  const int sec = n0 >> 10;  // 0 Q, 1 K, 2 V (1024-wide sections)
  if (sec < 2) {
    bfu* dst = (sec == 0) ? Qg : Kg;
    const float scale = (sec == 0) ? 0.18033688011112042f : 1.0f;  // log2e/8
#pragma unroll
    for (int ni = 0; ni < 8; ++ni) {
      int gn = n0 + wn * 128 + ni * 16 + l15;
      int rem = gn & 1023;
      int hh = rem >> 6, dk = rem & 63;
      float bv = bias[gn];
#pragma unroll
      for (int mi = 0; mi < 4; ++mi)
#pragma unroll
        for (int rg = 0; rg < 4; ++rg) {
          int gm = m0 + wm * 64 + mi * 16 + l4 * 4 + rg;
          int bb = gm >> 11, ll = gm & 2047;
          dst[(((size_t)(bb * H_ + hh)) * L_ + ll) * DK_ + dk] =
              f2bf((acc[mi][ni][rg] + bv) * scale);
        }
    }
  } else {
    // V: sigma^-1-permuted transpose via LDS, 2 passes of 128 cols (32 KB)
    __syncthreads();
#pragma unroll
    for (int p = 0; p < 2; ++p) {
      if (wn == p) {
#pragma unroll
        for (int ni = 0; ni < 8; ++ni) {
          int n_rel = ni * 16 + l15;              // [0,128) within pass
          int gn = n0 + p * 128 + n_rel;
          float bv = bias[gn];
          int swzn = (n_rel & 7) << 4;
#pragma unroll
          for (int mi = 0; mi < 4; ++mi) {
            int m_base = wm * 64 + mi * 16 + l4 * 4;
            int k6 = m_base & 63;
            int p0 = (m_base & ~63) |
                     ((k6 & 32) | (((k6 >> 2) & 3) << 3) | (((k6 >> 4) & 1) << 2));
            float v0 = acc[mi][ni][0] + bv, v1 = acc[mi][ni][1] + bv;
            float v2 = acc[mi][ni][2] + bv, v3 = acc[mi][ni][3] + bv;
            uint32_t w01, w23;
            asm("v_cvt_pk_bf16_f32 %0, %1, %2" : "=v"(w01) : "v"(v0), "v"(v1));
            asm("v_cvt_pk_bf16_f32 %0, %1, %2" : "=v"(w23) : "v"(v2), "v"(v3));
            *(uint32_t*)((char*)As + n_rel * 256 + ((2 * p0) ^ swzn)) = w01;
            *(uint32_t*)((char*)As + n_rel * 256 + ((2 * p0 + 4) ^ swzn)) = w23;
          }
        }
      }
      __syncthreads();
      int n = tid >> 1;
      int cb = (tid & 1) * 8;
      int gnn = n0 + p * 128 + n;
      int hh = (gnn >> 6) & 15, dk = gnn & 63;
      size_t rowbase =
          (((size_t)((m0 >> 11) * H_ + hh)) * DK_ + dk) * L_ + (m0 & 2047);
#pragma unroll
      for (int j = 0; j < 8; ++j) {
        int ch = cb + j;
        bf16x8 vv = *(const bf16x8*)((char*)As + n * 256 +
                                     ((ch * 16) ^ ((n & 7) << 4)));
        *(bf16x8*)(Vtg + rowbase + ch * 8) = vv;
      }
      __syncthreads();
    }
  }
}

// ---------------- gemm1: reg-B GEMM (per-wave 64x64, round-11 kernel) ------

template <int EPI>
__global__ __launch_bounds__(256, 2) void gemm_r(
    const bfu* __restrict__ A, const bfu* __restrict__ Bp,
    const float* __restrict__ bias, bfu* __restrict__ Qg, bfu* __restrict__ Kg,
    bfu* __restrict__ Vtg, float* __restrict__ Out, int M, int N, int K) {
  __shared__ __align__(16) bfu As[2][128 * 64];  // 32 KB total
  const int tid = threadIdx.x;
  const int lane = tid & 63;
  const int w = tid >> 6;
  const int wm = w >> 1, wn = w & 1;
  const int l15 = lane & 15, l4 = lane >> 4;

  const int nwg = gridDim.x;
  const int cpx = nwg >> 3;
  const int bid = (int)blockIdx.x;
  const int swz = (bid & 7) * cpx + (bid >> 3);
  const int NTt = N / 128;
  const int m0 = ((swz & 7) + 8 * (swz / (8 * NTt))) * 128;
  const int n0 = ((swz >> 3) % NTt) * 128;
  const int K8 = K >> 3;

  auto stageA = [&](int t) {
    char* lb = (char*)As[t & 1];
#pragma unroll
    for (int j = 0; j < 4; ++j) {
      int idx = j * 256 + tid;
      int row = idx >> 3, c16p = idx & 7, c16 = c16p ^ (row & 7);
      gll16(A + (size_t)(m0 + row) * K + t * 64 + c16 * 8,
            lb + row * 128 + c16p * 16);
    }
  };

  const size_t bbase = ((size_t)((n0 + wn * 64) >> 4)) * K8;
  auto loadB = [&](int t, bf16x8 (&br)[4][2]) {
#pragma unroll
    for (int ni = 0; ni < 4; ++ni)
#pragma unroll
      for (int kk = 0; kk < 2; ++kk)
        br[ni][kk] = *(const bf16x8*)(
            Bp + (bbase + (size_t)ni * K8 + t * 8 + kk * 4 + l4) * 128 + l15 * 8);
  };

  f32x4 acc[4][4] = {};
  bf16x8 af[4][2], brA[4][2], brB[4][2];

  auto lda = [&](int t) {
    const char* base = (const char*)As[t & 1];
#pragma unroll
    for (int mi = 0; mi < 4; ++mi)
#pragma unroll
      for (int kk = 0; kk < 2; ++kk) {
        int row = wm * 64 + mi * 16 + l15;
        int ch = (kk * 4 + l4) ^ (row & 7);
        af[mi][kk] = *(const bf16x8*)(base + row * 128 + ch * 16);
      }
  };
  auto mm_all = [&](bf16x8 (&br)[4][2]) {
    __builtin_amdgcn_s_setprio(1);
#pragma unroll
    for (int kk = 0; kk < 2; ++kk)
#pragma unroll
      for (int mi = 0; mi < 4; ++mi)
#pragma unroll
        for (int ni = 0; ni < 4; ++ni)
          acc[mi][ni] = MFMA(af[mi][kk], br[ni][kk], acc[mi][ni]);
    __builtin_amdgcn_s_setprio(0);
  };

  const int NT = K >> 6;  // even
  stageA(0);
  __builtin_amdgcn_sched_barrier(0);
  loadB(0, brA);
  loadB(1, brB);

  for (int t = 0; t < NT; t += 2) {
    VMCNT(8); BARRIER();
    lda(t);
    stageA(t + 1);
    __builtin_amdgcn_sched_barrier(0);
    mm_all(brA);
    if (t + 2 < NT) loadB(t + 2, brA);
    if (t + 2 < NT) { VMCNT(8); } else { VMCNT(0); }
    BARRIER();
    lda(t + 1);
    if (t + 2 < NT) stageA(t + 2);
    __builtin_amdgcn_sched_barrier(0);
    mm_all(brB);
    if (t + 3 < NT) loadB(t + 3, brB);
  }

  if constexpr (EPI == 1) {
#pragma unroll
    for (int ni = 0; ni < 4; ++ni) {
      int gn = n0 + wn * 64 + ni * 16 + l15;
      float bv = bias[gn];
#pragma unroll
      for (int mi = 0; mi < 4; ++mi)
#pragma unroll
        for (int rg = 0; rg < 4; ++rg) {
          int gm = m0 + wm * 64 + mi * 16 + l4 * 4 + rg;
          Out[(size_t)gm * N + gn] = acc[mi][ni][rg] + bv;
        }
    }
  }
}

// ---------------- flash attention v3 (causal) ----------------

__global__ __launch_bounds__(256, 3) void attn(const bfu* __restrict__ Qg,
                                               const bfu* __restrict__ Kg,
                                               const bfu* __restrict__ Vtg,
                                               bfu* __restrict__ Ao) {
  __shared__ __align__(16) bfu Ks[2 * 64 * 64];
  __shared__ __align__(16) bfu Vs[2 * 64 * 64];

  const int tid = threadIdx.x;
  const int lane = tid & 63;
  const int w = tid >> 6;
  const int l15 = lane & 15, l4 = lane >> 4;

  const int hid = blockIdx.x;            // 512 blocks
  const int xcd = hid & 7, slot = hid >> 3;
  const int bh = xcd * 8 + (slot >> 3);  // 8 bh per XCD
  const int p = slot & 7;
  const int b = bh >> 4, h = bh & 15;

  for (int seg = 0; seg < 2; ++seg) {
    const int qb = (seg == 0) ? p : 15 - p;   // 128-row superblock
    const int q0 = qb * 128;
    const int nt = 2 * qb + 2;
    const int q0w = q0 + w * 32;              // wave's first q row

    bf16x8 qf[2][2];
#pragma unroll
    for (int mi = 0; mi < 2; ++mi)
#pragma unroll
      for (int kk = 0; kk < 2; ++kk)
        qf[mi][kk] = *(const bf16x8*)(
            Qg + ((size_t)bh * L_ + q0w + mi * 16 + l15) * DK_ + kk * 32 + l4 * 8);

#pragma unroll
    for (int i = 0; i < 2; ++i) {
      int lb = i * 256 + tid;
      int r = lb >> 3, c16 = (lb & 7) ^ (r & 7);
      gll16(Kg + ((size_t)bh * L_ + r) * DK_ + c16 * 8, (char*)Ks + lb * 16);
      gll16(Vtg + ((size_t)bh * DK_ + r) * L_ + c16 * 8, (char*)Vs + lb * 16);
    }
    VMCNT(0);
    BARRIER();

    f32x4 acco[2][4] = {};
    float m[2] = {-1e30f, -1e30f};
    float l[2] = {0.f, 0.f};

    for (int t = 0; t < nt; ++t) {
      const int cur = t & 1;
      const int kv0 = t * 64;
      const char* Kc = (const char*)Ks + cur * 8192;
      const char* Vc = (const char*)Vs + cur * 8192;

      if (t + 1 < nt) {
        const int nb = (t + 1) & 1, nkv = (t + 1) * 64;
#pragma unroll
        for (int i = 0; i < 2; ++i) {
          int lb = i * 256 + tid;
          int r = lb >> 3, c16 = (lb & 7) ^ (r & 7);
          gll16(Kg + ((size_t)bh * L_ + nkv + r) * DK_ + c16 * 8,
                (char*)Ks + nb * 8192 + lb * 16);
          gll16(Vtg + ((size_t)bh * DK_ + r) * L_ + nkv + c16 * 8,
                (char*)Vs + nb * 8192 + lb * 16);
        }
        VMCNT(4);
      } else {
        VMCNT(0);
      }
      BARRIER();

      if (kv0 <= q0w + 31) {
        f32x4 s[2][4] = {};
        __builtin_amdgcn_s_setprio(1);
#pragma unroll
        for (int kk = 0; kk < 2; ++kk)
#pragma unroll
          for (int ni = 0; ni < 4; ++ni) {
            int r = ni * 16 + l15;
            int ch = (kk * 4 + l4) ^ (r & 7);
            bf16x8 kf = *(const bf16x8*)(Kc + r * 128 + ch * 16);
#pragma unroll
            for (int mi = 0; mi < 2; ++mi)
              s[mi][ni] = MFMA(kf, qf[mi][kk], s[mi][ni]);
          }
        __builtin_amdgcn_s_setprio(0);

        if (kv0 + 63 > q0w) {
#pragma unroll
          for (int mi = 0; mi < 2; ++mi) {
            int qg_ = q0w + mi * 16 + l15;
#pragma unroll
            for (int ni = 0; ni < 4; ++ni) {
              int kvg = kv0 + ni * 16 + l4 * 4;
#pragma unroll
              for (int rg = 0; rg < 4; ++rg)
                if (kvg + rg > qg_) s[mi][ni][rg] = -1e30f;
            }
          }
        }

        float mx[2];
#pragma unroll
        for (int mi = 0; mi < 2; ++mi) {
          float v = fmaxf(fmaxf(fmaxf(s[mi][0][0], s[mi][0][1]),
                                fmaxf(s[mi][0][2], s[mi][0][3])),
                          fmaxf(fmaxf(s[mi][1][0], s[mi][1][1]),
                                fmaxf(s[mi][1][2], s[mi][1][3])));
          v = fmaxf(v, fmaxf(fmaxf(fmaxf(s[mi][2][0], s[mi][2][1]),
                                   fmaxf(s[mi][2][2], s[mi][2][3])),
                             fmaxf(fmaxf(s[mi][3][0], s[mi][3][1]),
                                   fmaxf(s[mi][3][2], s[mi][3][3]))));
          v = fmaxf(v, __shfl_xor(v, 16));
          v = fmaxf(v, __shfl_xor(v, 32));
          mx[mi] = v;
        }
        float grow = fmaxf(mx[0] - m[0], mx[1] - m[1]);
        if (__any(grow > 11.0f)) {
#pragma unroll
          for (int mi = 0; mi < 2; ++mi) {
            float mn = fmaxf(m[mi], mx[mi]);
            float sc = __builtin_amdgcn_exp2f(m[mi] - mn);
            m[mi] = mn;
            l[mi] *= sc;
#pragma unroll
            for (int rg = 0; rg < 4; ++rg) {
              float scq = __shfl(sc, l4 * 4 + rg);
              acco[mi][0][rg] *= scq; acco[mi][1][rg] *= scq;
              acco[mi][2][rg] *= scq; acco[mi][3][rg] *= scq;
            }
          }
        }

        uint32_t pk[2][4][2];
#pragma unroll
        for (int mi = 0; mi < 2; ++mi)
#pragma unroll
          for (int ni = 0; ni < 4; ++ni) {
            float p0 = __builtin_amdgcn_exp2f(s[mi][ni][0] - m[mi]);
            float p1 = __builtin_amdgcn_exp2f(s[mi][ni][1] - m[mi]);
            float p2 = __builtin_amdgcn_exp2f(s[mi][ni][2] - m[mi]);
            float p3 = __builtin_amdgcn_exp2f(s[mi][ni][3] - m[mi]);
            l[mi] += (p0 + p1) + (p2 + p3);
            asm("v_cvt_pk_bf16_f32 %0, %1, %2" : "=v"(pk[mi][ni][0]) : "v"(p0), "v"(p1));
            asm("v_cvt_pk_bf16_f32 %0, %1, %2" : "=v"(pk[mi][ni][1]) : "v"(p2), "v"(p3));
          }

        __builtin_amdgcn_s_setprio(1);
#pragma unroll
        for (int kk = 0; kk < 2; ++kk) {
          union { uint32_t wd[4]; bf16x8 v; } u[2];
#pragma unroll
          for (int mi = 0; mi < 2; ++mi) {
            u[mi].wd[0] = pk[mi][2 * kk][0];
            u[mi].wd[1] = pk[mi][2 * kk][1];
            u[mi].wd[2] = pk[mi][2 * kk + 1][0];
            u[mi].wd[3] = pk[mi][2 * kk + 1][1];
          }
#pragma unroll
          for (int ni = 0; ni < 4; ++ni) {
            int r = ni * 16 + l15;
            int ch = (kk * 4 + l4) ^ (r & 7);
            bf16x8 vf = *(const bf16x8*)(Vc + r * 128 + ch * 16);
#pragma unroll
            for (int mi = 0; mi < 2; ++mi)
              acco[mi][ni] = MFMA(u[mi].v, vf, acco[mi][ni]);
          }
        }
        __builtin_amdgcn_s_setprio(0);
      }

      BARRIER();
    }

#pragma unroll
    for (int mi = 0; mi < 2; ++mi) {
      float ls = l[mi];
      ls += __shfl_xor(ls, 16);
      ls += __shfl_xor(ls, 32);
      float linv = 1.0f / ls;
#pragma unroll
      for (int rg = 0; rg < 4; ++rg) {
        float lq = __shfl(linv, l4 * 4 + rg);
        int q = q0w + mi * 16 + l4 * 4 + rg;
#pragma unroll
        for (int ni = 0; ni < 4; ++ni) {
          int d = ni * 16 + l15;
          Ao[((size_t)b * L_ + q) * D_ + h * DK_ + d] = f2bf(acco[mi][ni][rg] * lq);
        }
      }
    }
  }  // seg
}

// ---------------- launch ----------------

extern "C" void kernel_launch(void* const* d_in, const int* in_sizes, int n_in,
                              void* d_out, int out_size, void* d_ws, size_t ws_size,
                              hipStream_t stream) {
  const float* x = (const float*)d_in[0];
  const float* W_qkv = (const float*)d_in[1];
  const float* b_qkv = (const float*)d_in[2];
  const float* W_out = (const float*)d_in[3];
  const float* b_out = (const float*)d_in[4];
  float* out = (float*)d_out;

  char* ws = (char*)d_ws;
  bfu* xb     = (bfu*)(ws);                    // 16,777,216
  bfu* Wqkv_p = (bfu*)(ws + 16777216);         //  6,291,456
  bfu* Wout_p = (bfu*)(ws + 23068672);         //  2,097,152
  bfu* Qg     = (bfu*)(ws + 25165824);         // 16,777,216
  bfu* Kg     = (bfu*)(ws + 41943040);         // 16,777,216
  bfu* Vtg    = (bfu*)(ws + 58720256);         // 16,777,216
  bfu* Ao     = (bfu*)(ws + 75497472);         // 16,777,216

  cast_x<<<8192, 256, 0, stream>>>(x, xb, 2097152);
  wpack2<<<1536, 256, 0, stream>>>(W_qkv, Wqkv_p, 1024, 3072);
  wpack2<<<512, 256, 0, stream>>>(W_out, Wout_p, 1024, 1024);

  // gemm0: 128x256 tiles, grid 64m x 12n = 768
  gemm_n<<<768, 256, 0, stream>>>(xb, Wqkv_p, b_qkv, Qg, Kg, Vtg, 8192, 3072, 1024);
  attn<<<512, 256, 0, stream>>>(Qg, Kg, Vtg, Ao);
  // gemm1: 128x128 tiles, grid 64m x 8n = 512
  gemm_r<1><<<512, 256, 0, stream>>>(Ao, Wout_p, b_out, nullptr, nullptr, nullptr,
                                     out, 8192, 1024, 1024);
}